// Round 1
// baseline (694.445 us; speedup 1.0000x reference)
//
#include <hip/hip_runtime.h>
#include <cstdint>
#include <cstddef>

// ---------------- CSR build ----------------

__global__ void k_zero(int* __restrict__ p, int n) {
    int i = blockIdx.x * blockDim.x + threadIdx.x;
    if (i < n) p[i] = 0;
}

__global__ void k_hist(const int* __restrict__ dst, int* __restrict__ indeg, int E) {
    int e = blockIdx.x * blockDim.x + threadIdx.x;
    if (e < E) atomicAdd(&indeg[dst[e]], 1);
}

// Block-local exclusive scan: 256 threads x 4 elems = 1024 per block.
__global__ void k_scan_local(const int* __restrict__ in, int* __restrict__ out,
                             int* __restrict__ partials, int n) {
    __shared__ int s[256];
    int t = threadIdx.x;
    int base = blockIdx.x * 1024 + t * 4;
    int v0 = (base + 0) < n ? in[base + 0] : 0;
    int v1 = (base + 1) < n ? in[base + 1] : 0;
    int v2 = (base + 2) < n ? in[base + 2] : 0;
    int v3 = (base + 3) < n ? in[base + 3] : 0;
    int sum = v0 + v1 + v2 + v3;
    s[t] = sum;
    __syncthreads();
    for (int off = 1; off < 256; off <<= 1) {
        int x = (t >= off) ? s[t - off] : 0;
        __syncthreads();
        s[t] += x;
        __syncthreads();
    }
    int excl = s[t] - sum;  // exclusive prefix of this thread's 4-group
    if ((base + 0) < n) out[base + 0] = excl;
    if ((base + 1) < n) out[base + 1] = excl + v0;
    if ((base + 2) < n) out[base + 2] = excl + v0 + v1;
    if ((base + 3) < n) out[base + 3] = excl + v0 + v1 + v2;
    if (t == 255) partials[blockIdx.x] = s[255];
}

// Single-block exclusive scan of the per-block partials (np <= 256).
__global__ void k_scan_partials(int* __restrict__ partials, int np) {
    __shared__ int s[256];
    int t = threadIdx.x;
    int v = (t < np) ? partials[t] : 0;
    s[t] = v;
    __syncthreads();
    for (int off = 1; off < 256; off <<= 1) {
        int x = (t >= off) ? s[t - off] : 0;
        __syncthreads();
        s[t] += x;
        __syncthreads();
    }
    if (t < np) partials[t] = s[t] - v;
}

// Add block offsets, emit final row_ptr + cursor copy + dinv = rsqrt(indeg+1).
__global__ void k_finalize(int* __restrict__ row_ptr, const int* __restrict__ partials,
                           const int* __restrict__ indeg, int* __restrict__ cursor,
                           float* __restrict__ dinv, int n, int E) {
    int i = blockIdx.x * blockDim.x + threadIdx.x;
    if (i < n) {
        int rp = row_ptr[i] + partials[i >> 10];
        row_ptr[i] = rp;
        cursor[i] = rp;
        dinv[i] = rsqrtf((float)indeg[i] + 1.0f);  // +1 = self loop
        if (i == 0) row_ptr[n] = E;
    }
}

__global__ void k_fill(const int* __restrict__ src, const int* __restrict__ dst,
                       int* __restrict__ cursor, int* __restrict__ col, int E) {
    int e = blockIdx.x * blockDim.x + threadIdx.x;
    if (e < E) {
        int d = dst[e];
        int p = atomicAdd(&cursor[d], 1);
        col[p] = src[e];
    }
}

// ---------------- GEMMs (fp32 VALU, LDS-tiled, 4x4 / 2x4 register tiles) ----------

// H[N x 128] = X[N x 128] @ W[128 x 128]; grid = N/32 blocks of 256 threads.
__global__ __launch_bounds__(256) void k_gemm128(const float* __restrict__ X,
                                                 const float* __restrict__ W,
                                                 float* __restrict__ H) {
    __shared__ float Wl[32 * 128];  // 16 KB k-chunk of W
    __shared__ float Xs[32 * 32];   // 4 KB  x tile
    int t = threadIdx.x;
    size_t row0 = (size_t)blockIdx.x * 32;
    int r0 = (t >> 5) * 4;   // 8 row groups x 4 rows
    int c0 = (t & 31) * 4;   // 32 col groups x 4 cols
    int lr = t >> 3, lk = (t & 7) * 4;
    float acc[4][4] = {};
    for (int kc = 0; kc < 128; kc += 32) {
        __syncthreads();
        for (int idx = t; idx < 1024; idx += 256)
            ((float4*)Wl)[idx] = ((const float4*)W)[kc * 32 + idx];
        *(float4*)(Xs + lr * 32 + lk) =
            *(const float4*)(X + (row0 + lr) * 128 + kc + lk);
        __syncthreads();
        for (int kk = 0; kk < 32; kk += 4) {
            float a[4][4], wv[4][4];
            for (int r = 0; r < 4; r++) {
                float4 av = *(const float4*)(Xs + (r0 + r) * 32 + kk);
                a[r][0] = av.x; a[r][1] = av.y; a[r][2] = av.z; a[r][3] = av.w;
            }
            for (int j = 0; j < 4; j++) {
                float4 wq = *(const float4*)(Wl + (kk + j) * 128 + c0);
                wv[j][0] = wq.x; wv[j][1] = wq.y; wv[j][2] = wq.z; wv[j][3] = wq.w;
            }
            for (int r = 0; r < 4; r++)
                for (int j = 0; j < 4; j++)
                    for (int c = 0; c < 4; c++)
                        acc[r][c] += a[r][j] * wv[j][c];
        }
    }
    for (int r = 0; r < 4; r++) {
        float4 o = {acc[r][0], acc[r][1], acc[r][2], acc[r][3]};
        *(float4*)(H + (row0 + r0 + r) * 128 + c0) = o;
    }
}

// H[N x 64] = X[N x 128] @ W[128 x 64]; grid = N/32 blocks of 256 threads.
__global__ __launch_bounds__(256) void k_gemm64(const float* __restrict__ X,
                                                const float* __restrict__ W,
                                                float* __restrict__ H) {
    __shared__ float Wl[32 * 64];  // 8 KB
    __shared__ float Xs[32 * 32];  // 4 KB
    int t = threadIdx.x;
    size_t row0 = (size_t)blockIdx.x * 32;
    int r0 = (t >> 4) * 2;   // 16 row groups x 2 rows
    int c0 = (t & 15) * 4;   // 16 col groups x 4 cols
    int lr = t >> 3, lk = (t & 7) * 4;
    float acc[2][4] = {};
    for (int kc = 0; kc < 128; kc += 32) {
        __syncthreads();
        ((float4*)Wl)[t]       = ((const float4*)W)[kc * 16 + t];
        ((float4*)Wl)[t + 256] = ((const float4*)W)[kc * 16 + t + 256];
        *(float4*)(Xs + lr * 32 + lk) =
            *(const float4*)(X + (row0 + lr) * 128 + kc + lk);
        __syncthreads();
        for (int kk = 0; kk < 32; kk += 4) {
            float a[2][4], wv[4][4];
            for (int r = 0; r < 2; r++) {
                float4 av = *(const float4*)(Xs + (r0 + r) * 32 + kk);
                a[r][0] = av.x; a[r][1] = av.y; a[r][2] = av.z; a[r][3] = av.w;
            }
            for (int j = 0; j < 4; j++) {
                float4 wq = *(const float4*)(Wl + (kk + j) * 64 + c0);
                wv[j][0] = wq.x; wv[j][1] = wq.y; wv[j][2] = wq.z; wv[j][3] = wq.w;
            }
            for (int r = 0; r < 2; r++)
                for (int j = 0; j < 4; j++)
                    for (int c = 0; c < 4; c++)
                        acc[r][c] += a[r][j] * wv[j][c];
        }
    }
    for (int r = 0; r < 2; r++) {
        float4 o = {acc[r][0], acc[r][1], acc[r][2], acc[r][3]};
        *(float4*)(H + (row0 + r0 + r) * 64 + c0) = o;
    }
}

// ---------------- Pull-mode aggregation: one wave per node ----------------

// out[i] = relu( d_i * (sum_j d_j h_j + d_i h_i) + b ), 128 cols, lane holds 2 cols.
__global__ __launch_bounds__(256) void k_agg_relu(const float* __restrict__ h,
                                                  const float* __restrict__ dinv,
                                                  const int* __restrict__ row_ptr,
                                                  const int* __restrict__ col,
                                                  const float* __restrict__ bias,
                                                  float* __restrict__ out, int n) {
    int node = blockIdx.x * 4 + (threadIdx.x >> 6);
    if (node >= n) return;
    int lane = threadIdx.x & 63;
    float di = dinv[node];
    const float2* hp = (const float2*)h;
    float2 hv = hp[(size_t)node * 64 + lane];
    float ax = di * hv.x, ay = di * hv.y;  // self loop (pre-scaled)
    int pend = row_ptr[node + 1];
    for (int p = row_ptr[node]; p < pend; ++p) {
        int j = col[p];
        float dj = dinv[j];
        float2 v = hp[(size_t)j * 64 + lane];
        ax += dj * v.x;
        ay += dj * v.y;
    }
    ax = di * ax + bias[2 * lane];
    ay = di * ay + bias[2 * lane + 1];
    ax = ax > 0.f ? ax : 0.f;
    ay = ay > 0.f ? ay : 0.f;
    float2 o = {ax, ay};
    ((float2*)out)[(size_t)node * 64 + lane] = o;
}

// 64 cols, lane = col. Fused log_softmax across the wave.
__global__ __launch_bounds__(256) void k_agg_lsm(const float* __restrict__ h,
                                                 const float* __restrict__ dinv,
                                                 const int* __restrict__ row_ptr,
                                                 const int* __restrict__ col,
                                                 const float* __restrict__ bias,
                                                 float* __restrict__ out, int n) {
    int node = blockIdx.x * 4 + (threadIdx.x >> 6);
    if (node >= n) return;
    int lane = threadIdx.x & 63;
    float di = dinv[node];
    float acc = di * h[(size_t)node * 64 + lane];
    int pend = row_ptr[node + 1];
    for (int p = row_ptr[node]; p < pend; ++p) {
        int j = col[p];
        acc += dinv[j] * h[(size_t)j * 64 + lane];
    }
    float v = di * acc + bias[lane];
    float m = v;
    for (int off = 32; off; off >>= 1) m = fmaxf(m, __shfl_xor(m, off));
    float e = __expf(v - m);
    float s = e;
    for (int off = 32; off; off >>= 1) s += __shfl_xor(s, off);
    out[(size_t)node * 64 + lane] = v - m - __logf(s);
}

// ---------------- launcher ----------------

extern "C" void kernel_launch(void* const* d_in, const int* in_sizes, int n_in,
                              void* d_out, int out_size, void* d_ws, size_t ws_size,
                              hipStream_t stream) {
    const float* x  = (const float*)d_in[0];
    const int*   ei = (const int*)d_in[1];
    const float* W1 = (const float*)d_in[2];
    const float* b1 = (const float*)d_in[3];
    const float* W2 = (const float*)d_in[4];
    const float* b2 = (const float*)d_in[5];
    float* out = (float*)d_out;

    const int N = in_sizes[0] / 128;   // 100000
    const int E = in_sizes[1] / 2;     // 1600000
    const int* src = ei;       // edge_index[0]
    const int* dst = ei + E;   // edge_index[1]

    // workspace carve (256B aligned)
    char* w = (char*)d_ws;
    size_t off = 0;
    auto alloc = [&](size_t bytes) -> void* {
        void* p = w + off;
        off += (bytes + 255) & ~(size_t)255;
        return p;
    };
    int*   indeg    = (int*)alloc((size_t)N * 4);
    int*   row_ptr  = (int*)alloc((size_t)(N + 1) * 4);
    int*   cursor   = (int*)alloc((size_t)N * 4);
    int*   colarr   = (int*)alloc((size_t)E * 4);
    int*   partials = (int*)alloc(256 * 4);
    float* dinv     = (float*)alloc((size_t)N * 4);
    float* h1       = (float*)alloc((size_t)N * 128 * 4);
    float* a1       = (float*)alloc((size_t)N * 128 * 4);
    float* h2       = (float*)alloc((size_t)N * 64 * 4);
    (void)ws_size; (void)n_in; (void)out_size;

    int nscan = (N + 1023) / 1024;  // 98 <= 256

    k_zero<<<(N + 255) / 256, 256, 0, stream>>>(indeg, N);
    k_hist<<<(E + 255) / 256, 256, 0, stream>>>(dst, indeg, E);
    k_scan_local<<<nscan, 256, 0, stream>>>(indeg, row_ptr, partials, N);
    k_scan_partials<<<1, 256, 0, stream>>>(partials, nscan);
    k_finalize<<<(N + 255) / 256, 256, 0, stream>>>(row_ptr, partials, indeg, cursor,
                                                    dinv, N, E);
    k_fill<<<(E + 255) / 256, 256, 0, stream>>>(src, dst, cursor, colarr, E);

    k_gemm128<<<N / 32, 256, 0, stream>>>(x, W1, h1);
    k_agg_relu<<<(N + 3) / 4, 256, 0, stream>>>(h1, dinv, row_ptr, colarr, b1, a1, N);
    k_gemm64<<<N / 32, 256, 0, stream>>>(a1, W2, h2);
    k_agg_lsm<<<(N + 3) / 4, 256, 0, stream>>>(h2, dinv, row_ptr, colarr, b2, out, N);
}

// Round 2
// 544.450 us; speedup vs baseline: 1.2755x; 1.2755x over previous
//
#include <hip/hip_runtime.h>
#include <cstdint>
#include <cstddef>

// ---------------- CSR build ----------------

__global__ void k_zero(int* __restrict__ p, int n) {
    int i = blockIdx.x * blockDim.x + threadIdx.x;
    if (i < n) p[i] = 0;
}

__global__ void k_hist(const int* __restrict__ dst, int* __restrict__ indeg, int E) {
    int e = blockIdx.x * blockDim.x + threadIdx.x;
    if (e < E) atomicAdd(&indeg[dst[e]], 1);
}

// Block-local exclusive scan: 256 threads x 4 elems = 1024 per block.
__global__ void k_scan_local(const int* __restrict__ in, int* __restrict__ out,
                             int* __restrict__ partials, int n) {
    __shared__ int s[256];
    int t = threadIdx.x;
    int base = blockIdx.x * 1024 + t * 4;
    int v0 = (base + 0) < n ? in[base + 0] : 0;
    int v1 = (base + 1) < n ? in[base + 1] : 0;
    int v2 = (base + 2) < n ? in[base + 2] : 0;
    int v3 = (base + 3) < n ? in[base + 3] : 0;
    int sum = v0 + v1 + v2 + v3;
    s[t] = sum;
    __syncthreads();
    for (int off = 1; off < 256; off <<= 1) {
        int x = (t >= off) ? s[t - off] : 0;
        __syncthreads();
        s[t] += x;
        __syncthreads();
    }
    int excl = s[t] - sum;  // exclusive prefix of this thread's 4-group
    if ((base + 0) < n) out[base + 0] = excl;
    if ((base + 1) < n) out[base + 1] = excl + v0;
    if ((base + 2) < n) out[base + 2] = excl + v0 + v1;
    if ((base + 3) < n) out[base + 3] = excl + v0 + v1 + v2;
    if (t == 255) partials[blockIdx.x] = s[255];
}

// Single-block exclusive scan of the per-block partials (np <= 256).
__global__ void k_scan_partials(int* __restrict__ partials, int np) {
    __shared__ int s[256];
    int t = threadIdx.x;
    int v = (t < np) ? partials[t] : 0;
    s[t] = v;
    __syncthreads();
    for (int off = 1; off < 256; off <<= 1) {
        int x = (t >= off) ? s[t - off] : 0;
        __syncthreads();
        s[t] += x;
        __syncthreads();
    }
    if (t < np) partials[t] = s[t] - v;
}

// Add block offsets, emit final row_ptr + cursor copy + dinv = rsqrt(indeg+1).
__global__ void k_finalize(int* __restrict__ row_ptr, const int* __restrict__ partials,
                           const int* __restrict__ indeg, int* __restrict__ cursor,
                           float* __restrict__ dinv, int n, int E) {
    int i = blockIdx.x * blockDim.x + threadIdx.x;
    if (i < n) {
        int rp = row_ptr[i] + partials[i >> 10];
        row_ptr[i] = rp;
        cursor[i] = rp;
        dinv[i] = rsqrtf((float)indeg[i] + 1.0f);  // +1 = self loop
        if (i == 0) row_ptr[n] = E;
    }
}

__global__ void k_fill(const int* __restrict__ src, const int* __restrict__ dst,
                       int* __restrict__ cursor, int* __restrict__ col, int E) {
    int e = blockIdx.x * blockDim.x + threadIdx.x;
    if (e < E) {
        int d = dst[e];
        int p = atomicAdd(&cursor[d], 1);
        col[p] = src[e];
    }
}

// ---------------- GEMMs (fp32 VALU, LDS-tiled) — epilogue scales row r by dinv[r] ---

// H[N x 128] = dinv[row] * (X[N x 128] @ W[128 x 128]); grid = N/32 blocks.
__global__ __launch_bounds__(256) void k_gemm128(const float* __restrict__ X,
                                                 const float* __restrict__ W,
                                                 const float* __restrict__ dinv,
                                                 float* __restrict__ H) {
    __shared__ float Wl[32 * 128];  // 16 KB k-chunk of W
    __shared__ float Xs[32 * 32];   // 4 KB  x tile
    int t = threadIdx.x;
    size_t row0 = (size_t)blockIdx.x * 32;
    int r0 = (t >> 5) * 4;   // 8 row groups x 4 rows
    int c0 = (t & 31) * 4;   // 32 col groups x 4 cols
    int lr = t >> 3, lk = (t & 7) * 4;
    float acc[4][4] = {};
    for (int kc = 0; kc < 128; kc += 32) {
        __syncthreads();
        for (int idx = t; idx < 1024; idx += 256)
            ((float4*)Wl)[idx] = ((const float4*)W)[kc * 32 + idx];
        *(float4*)(Xs + lr * 32 + lk) =
            *(const float4*)(X + (row0 + lr) * 128 + kc + lk);
        __syncthreads();
        for (int kk = 0; kk < 32; kk += 4) {
            float a[4][4], wv[4][4];
            for (int r = 0; r < 4; r++) {
                float4 av = *(const float4*)(Xs + (r0 + r) * 32 + kk);
                a[r][0] = av.x; a[r][1] = av.y; a[r][2] = av.z; a[r][3] = av.w;
            }
            for (int j = 0; j < 4; j++) {
                float4 wq = *(const float4*)(Wl + (kk + j) * 128 + c0);
                wv[j][0] = wq.x; wv[j][1] = wq.y; wv[j][2] = wq.z; wv[j][3] = wq.w;
            }
            for (int r = 0; r < 4; r++)
                for (int j = 0; j < 4; j++)
                    for (int c = 0; c < 4; c++)
                        acc[r][c] += a[r][j] * wv[j][c];
        }
    }
    for (int r = 0; r < 4; r++) {
        float di = dinv[row0 + r0 + r];
        float4 o = {di * acc[r][0], di * acc[r][1], di * acc[r][2], di * acc[r][3]};
        *(float4*)(H + (row0 + r0 + r) * 128 + c0) = o;
    }
}

// H[N x 64] = dinv[row] * (X[N x 128] @ W[128 x 64]); grid = N/32 blocks.
__global__ __launch_bounds__(256) void k_gemm64(const float* __restrict__ X,
                                                const float* __restrict__ W,
                                                const float* __restrict__ dinv,
                                                float* __restrict__ H) {
    __shared__ float Wl[32 * 64];  // 8 KB
    __shared__ float Xs[32 * 32];  // 4 KB
    int t = threadIdx.x;
    size_t row0 = (size_t)blockIdx.x * 32;
    int r0 = (t >> 4) * 2;   // 16 row groups x 2 rows
    int c0 = (t & 15) * 4;   // 16 col groups x 4 cols
    int lr = t >> 3, lk = (t & 7) * 4;
    float acc[2][4] = {};
    for (int kc = 0; kc < 128; kc += 32) {
        __syncthreads();
        ((float4*)Wl)[t]       = ((const float4*)W)[kc * 16 + t];
        ((float4*)Wl)[t + 256] = ((const float4*)W)[kc * 16 + t + 256];
        *(float4*)(Xs + lr * 32 + lk) =
            *(const float4*)(X + (row0 + lr) * 128 + kc + lk);
        __syncthreads();
        for (int kk = 0; kk < 32; kk += 4) {
            float a[2][4], wv[4][4];
            for (int r = 0; r < 2; r++) {
                float4 av = *(const float4*)(Xs + (r0 + r) * 32 + kk);
                a[r][0] = av.x; a[r][1] = av.y; a[r][2] = av.z; a[r][3] = av.w;
            }
            for (int j = 0; j < 4; j++) {
                float4 wq = *(const float4*)(Wl + (kk + j) * 64 + c0);
                wv[j][0] = wq.x; wv[j][1] = wq.y; wv[j][2] = wq.z; wv[j][3] = wq.w;
            }
            for (int r = 0; r < 2; r++)
                for (int j = 0; j < 4; j++)
                    for (int c = 0; c < 4; c++)
                        acc[r][c] += a[r][j] * wv[j][c];
        }
    }
    for (int r = 0; r < 2; r++) {
        float di = dinv[row0 + r0 + r];
        float4 o = {di * acc[r][0], di * acc[r][1], di * acc[r][2], di * acc[r][3]};
        *(float4*)(H + (row0 + r0 + r) * 64 + c0) = o;
    }
}

// ---------------- Pull-mode aggregation: one wave per node, MLP-unrolled ----------

// hs rows are pre-scaled by dinv[row]. out_i = relu(di*(Σ_nbr hs_j + hs_i) + b).
__global__ __launch_bounds__(256) void k_agg_relu(const float* __restrict__ hs,
                                                  const float* __restrict__ dinv,
                                                  const int* __restrict__ row_ptr,
                                                  const int* __restrict__ col,
                                                  const float* __restrict__ bias,
                                                  float* __restrict__ out, int n) {
    int node = blockIdx.x * 4 + (threadIdx.x >> 6);
    if (node >= n) return;
    int lane = threadIdx.x & 63;
    const float2* hp = (const float2*)hs;
    float2 self = hp[(size_t)node * 64 + lane];  // = di * h_i
    float ax = self.x, ay = self.y;
    int p0 = row_ptr[node], p1 = row_ptr[node + 1];
    for (int base = p0; base < p1; base += 64) {
        int nb = min(64, p1 - base);
        int myc = col[base + min(lane, nb - 1)];  // lane-parallel index prefetch
        int k = 0;
        for (; k + 4 <= nb; k += 4) {
            int j0 = __shfl(myc, k);
            int j1 = __shfl(myc, k + 1);
            int j2 = __shfl(myc, k + 2);
            int j3 = __shfl(myc, k + 3);
            float2 v0 = hp[(size_t)j0 * 64 + lane];
            float2 v1 = hp[(size_t)j1 * 64 + lane];
            float2 v2 = hp[(size_t)j2 * 64 + lane];
            float2 v3 = hp[(size_t)j3 * 64 + lane];
            ax += (v0.x + v1.x) + (v2.x + v3.x);
            ay += (v0.y + v1.y) + (v2.y + v3.y);
        }
        for (; k < nb; ++k) {
            int j = __shfl(myc, k);
            float2 v = hp[(size_t)j * 64 + lane];
            ax += v.x;
            ay += v.y;
        }
    }
    float di = dinv[node];
    ax = fmaf(di, ax, bias[2 * lane]);
    ay = fmaf(di, ay, bias[2 * lane + 1]);
    ax = ax > 0.f ? ax : 0.f;
    ay = ay > 0.f ? ay : 0.f;
    float2 o = {ax, ay};
    ((float2*)out)[(size_t)node * 64 + lane] = o;
}

// 64 cols, lane = col. hs pre-scaled. Fused log_softmax across the wave.
__global__ __launch_bounds__(256) void k_agg_lsm(const float* __restrict__ hs,
                                                 const float* __restrict__ dinv,
                                                 const int* __restrict__ row_ptr,
                                                 const int* __restrict__ col,
                                                 const float* __restrict__ bias,
                                                 float* __restrict__ out, int n) {
    int node = blockIdx.x * 4 + (threadIdx.x >> 6);
    if (node >= n) return;
    int lane = threadIdx.x & 63;
    float acc = hs[(size_t)node * 64 + lane];  // self term
    int p0 = row_ptr[node], p1 = row_ptr[node + 1];
    for (int base = p0; base < p1; base += 64) {
        int nb = min(64, p1 - base);
        int myc = col[base + min(lane, nb - 1)];
        int k = 0;
        for (; k + 4 <= nb; k += 4) {
            int j0 = __shfl(myc, k);
            int j1 = __shfl(myc, k + 1);
            int j2 = __shfl(myc, k + 2);
            int j3 = __shfl(myc, k + 3);
            float v0 = hs[(size_t)j0 * 64 + lane];
            float v1 = hs[(size_t)j1 * 64 + lane];
            float v2 = hs[(size_t)j2 * 64 + lane];
            float v3 = hs[(size_t)j3 * 64 + lane];
            acc += (v0 + v1) + (v2 + v3);
        }
        for (; k < nb; ++k) {
            int j = __shfl(myc, k);
            acc += hs[(size_t)j * 64 + lane];
        }
    }
    float v = fmaf(dinv[node], acc, bias[lane]);
    float m = v;
    for (int off = 32; off; off >>= 1) m = fmaxf(m, __shfl_xor(m, off));
    float e = __expf(v - m);
    float s = e;
    for (int off = 32; off; off >>= 1) s += __shfl_xor(s, off);
    out[(size_t)node * 64 + lane] = v - m - __logf(s);
}

// ---------------- launcher ----------------

extern "C" void kernel_launch(void* const* d_in, const int* in_sizes, int n_in,
                              void* d_out, int out_size, void* d_ws, size_t ws_size,
                              hipStream_t stream) {
    const float* x  = (const float*)d_in[0];
    const int*   ei = (const int*)d_in[1];
    const float* W1 = (const float*)d_in[2];
    const float* b1 = (const float*)d_in[3];
    const float* W2 = (const float*)d_in[4];
    const float* b2 = (const float*)d_in[5];
    float* out = (float*)d_out;

    const int N = in_sizes[0] / 128;   // 100000
    const int E = in_sizes[1] / 2;     // 1600000
    const int* src = ei;       // edge_index[0]
    const int* dst = ei + E;   // edge_index[1]

    // workspace carve (256B aligned)
    char* w = (char*)d_ws;
    size_t off = 0;
    auto alloc = [&](size_t bytes) -> void* {
        void* p = w + off;
        off += (bytes + 255) & ~(size_t)255;
        return p;
    };
    int*   indeg    = (int*)alloc((size_t)N * 4);
    int*   row_ptr  = (int*)alloc((size_t)(N + 1) * 4);
    int*   cursor   = (int*)alloc((size_t)N * 4);
    int*   colarr   = (int*)alloc((size_t)E * 4);
    int*   partials = (int*)alloc(256 * 4);
    float* dinv     = (float*)alloc((size_t)N * 4);
    float* h1s      = (float*)alloc((size_t)N * 128 * 4);  // dinv-scaled X@W1
    float* a1       = (float*)alloc((size_t)N * 128 * 4);  // relu layer-1 out
    float* h2s      = (float*)alloc((size_t)N * 64 * 4);   // dinv-scaled a1@W2
    (void)ws_size; (void)n_in; (void)out_size;

    int nscan = (N + 1023) / 1024;  // 98 <= 256

    k_zero<<<(N + 255) / 256, 256, 0, stream>>>(indeg, N);
    k_hist<<<(E + 255) / 256, 256, 0, stream>>>(dst, indeg, E);
    k_scan_local<<<nscan, 256, 0, stream>>>(indeg, row_ptr, partials, N);
    k_scan_partials<<<1, 256, 0, stream>>>(partials, nscan);
    k_finalize<<<(N + 255) / 256, 256, 0, stream>>>(row_ptr, partials, indeg, cursor,
                                                    dinv, N, E);
    k_fill<<<(E + 255) / 256, 256, 0, stream>>>(src, dst, cursor, colarr, E);

    k_gemm128<<<N / 32, 256, 0, stream>>>(x, W1, dinv, h1s);
    k_agg_relu<<<(N + 3) / 4, 256, 0, stream>>>(h1s, dinv, row_ptr, colarr, b1, a1, N);
    k_gemm64<<<N / 32, 256, 0, stream>>>(a1, W2, dinv, h2s);
    k_agg_lsm<<<(N + 3) / 4, 256, 0, stream>>>(h2s, dinv, row_ptr, colarr, b2, out, N);
}

// Round 3
// 503.379 us; speedup vs baseline: 1.3796x; 1.0816x over previous
//
#include <hip/hip_runtime.h>
#include <cstdint>
#include <cstddef>

// ---------------- CSR build (XCD-partitioned: blocks with equal blockIdx%8
// own one contiguous node range, so cursor atomics + col lines stay in one
// XCD's L2 — kills cross-XCD line ping-pong / write amplification) ----------

#define NPART 8

__global__ void k_zero(int* __restrict__ p, int n) {
    int i = blockIdx.x * blockDim.x + threadIdx.x;
    if (i < n) p[i] = 0;
}

// Each partition x = blockIdx%8 histograms only nodes [x*npp, x*npp+npp).
__global__ __launch_bounds__(256) void k_hist_x(const int* __restrict__ dst,
                                                int* __restrict__ indeg,
                                                int E, int npp, int N) {
    int part = blockIdx.x & (NPART - 1);
    int rep  = blockIdx.x >> 3;
    int nrep = gridDim.x >> 3;
    int lo = part * npp;
    int hi = min(N, lo + npp);
    int t = rep * blockDim.x + threadIdx.x;
    int stride = nrep * blockDim.x;
    int E4 = E >> 2;
    const int4* d4 = (const int4*)dst;
    for (int i = t; i < E4; i += stride) {
        int4 d = d4[i];
        if (d.x >= lo && d.x < hi) atomicAdd(&indeg[d.x], 1);
        if (d.y >= lo && d.y < hi) atomicAdd(&indeg[d.y], 1);
        if (d.z >= lo && d.z < hi) atomicAdd(&indeg[d.z], 1);
        if (d.w >= lo && d.w < hi) atomicAdd(&indeg[d.w], 1);
    }
    for (int e = E4 * 4 + t; e < E; e += stride) {
        int d = dst[e];
        if (d >= lo && d < hi) atomicAdd(&indeg[d], 1);
    }
}

// Block-local exclusive scan: 256 threads x 4 elems = 1024 per block.
__global__ void k_scan_local(const int* __restrict__ in, int* __restrict__ out,
                             int* __restrict__ partials, int n) {
    __shared__ int s[256];
    int t = threadIdx.x;
    int base = blockIdx.x * 1024 + t * 4;
    int v0 = (base + 0) < n ? in[base + 0] : 0;
    int v1 = (base + 1) < n ? in[base + 1] : 0;
    int v2 = (base + 2) < n ? in[base + 2] : 0;
    int v3 = (base + 3) < n ? in[base + 3] : 0;
    int sum = v0 + v1 + v2 + v3;
    s[t] = sum;
    __syncthreads();
    for (int off = 1; off < 256; off <<= 1) {
        int x = (t >= off) ? s[t - off] : 0;
        __syncthreads();
        s[t] += x;
        __syncthreads();
    }
    int excl = s[t] - sum;
    if ((base + 0) < n) out[base + 0] = excl;
    if ((base + 1) < n) out[base + 1] = excl + v0;
    if ((base + 2) < n) out[base + 2] = excl + v0 + v1;
    if ((base + 3) < n) out[base + 3] = excl + v0 + v1 + v2;
    if (t == 255) partials[blockIdx.x] = s[255];
}

// Single-block exclusive scan of the per-block partials (np <= 256).
__global__ void k_scan_partials(int* __restrict__ partials, int np) {
    __shared__ int s[256];
    int t = threadIdx.x;
    int v = (t < np) ? partials[t] : 0;
    s[t] = v;
    __syncthreads();
    for (int off = 1; off < 256; off <<= 1) {
        int x = (t >= off) ? s[t - off] : 0;
        __syncthreads();
        s[t] += x;
        __syncthreads();
    }
    if (t < np) partials[t] = s[t] - v;
}

// Add block offsets, emit final row_ptr + cursor copy + dinv = rsqrt(indeg+1).
__global__ void k_finalize(int* __restrict__ row_ptr, const int* __restrict__ partials,
                           const int* __restrict__ indeg, int* __restrict__ cursor,
                           float* __restrict__ dinv, int n, int E) {
    int i = blockIdx.x * blockDim.x + threadIdx.x;
    if (i < n) {
        int rp = row_ptr[i] + partials[i >> 10];
        row_ptr[i] = rp;
        cursor[i] = rp;
        dinv[i] = rsqrtf((float)indeg[i] + 1.0f);  // +1 = self loop
        if (i == 0) row_ptr[n] = E;
    }
}

// Each partition fills only its own node range; cursor + col lines stay L2-local.
__global__ __launch_bounds__(256) void k_fill_x(const int* __restrict__ src,
                                                const int* __restrict__ dst,
                                                int* __restrict__ cursor,
                                                int* __restrict__ col,
                                                int E, int npp, int N) {
    int part = blockIdx.x & (NPART - 1);
    int rep  = blockIdx.x >> 3;
    int nrep = gridDim.x >> 3;
    int lo = part * npp;
    int hi = min(N, lo + npp);
    int t = rep * blockDim.x + threadIdx.x;
    int stride = nrep * blockDim.x;
    int E4 = E >> 2;
    const int4* d4 = (const int4*)dst;
    const int4* s4 = (const int4*)src;
    for (int i = t; i < E4; i += stride) {
        int4 d = d4[i];
        int4 s = s4[i];
        if (d.x >= lo && d.x < hi) { int p = atomicAdd(&cursor[d.x], 1); col[p] = s.x; }
        if (d.y >= lo && d.y < hi) { int p = atomicAdd(&cursor[d.y], 1); col[p] = s.y; }
        if (d.z >= lo && d.z < hi) { int p = atomicAdd(&cursor[d.z], 1); col[p] = s.z; }
        if (d.w >= lo && d.w < hi) { int p = atomicAdd(&cursor[d.w], 1); col[p] = s.w; }
    }
    for (int e = E4 * 4 + t; e < E; e += stride) {
        int d = dst[e];
        if (d >= lo && d < hi) { int p = atomicAdd(&cursor[d], 1); col[p] = src[e]; }
    }
}

// ---------------- GEMMs (fp32 VALU, LDS-tiled) — epilogue scales row r by dinv[r] ---

// H[N x 128] = dinv[row] * (X[N x 128] @ W[128 x 128]); grid = N/32 blocks.
__global__ __launch_bounds__(256) void k_gemm128(const float* __restrict__ X,
                                                 const float* __restrict__ W,
                                                 const float* __restrict__ dinv,
                                                 float* __restrict__ H) {
    __shared__ float Wl[32 * 128];  // 16 KB k-chunk of W
    __shared__ float Xs[32 * 32];   // 4 KB  x tile
    int t = threadIdx.x;
    size_t row0 = (size_t)blockIdx.x * 32;
    int r0 = (t >> 5) * 4;   // 8 row groups x 4 rows
    int c0 = (t & 31) * 4;   // 32 col groups x 4 cols
    int lr = t >> 3, lk = (t & 7) * 4;
    float acc[4][4] = {};
    for (int kc = 0; kc < 128; kc += 32) {
        __syncthreads();
        for (int idx = t; idx < 1024; idx += 256)
            ((float4*)Wl)[idx] = ((const float4*)W)[kc * 32 + idx];
        *(float4*)(Xs + lr * 32 + lk) =
            *(const float4*)(X + (row0 + lr) * 128 + kc + lk);
        __syncthreads();
        for (int kk = 0; kk < 32; kk += 4) {
            float a[4][4], wv[4][4];
            for (int r = 0; r < 4; r++) {
                float4 av = *(const float4*)(Xs + (r0 + r) * 32 + kk);
                a[r][0] = av.x; a[r][1] = av.y; a[r][2] = av.z; a[r][3] = av.w;
            }
            for (int j = 0; j < 4; j++) {
                float4 wq = *(const float4*)(Wl + (kk + j) * 128 + c0);
                wv[j][0] = wq.x; wv[j][1] = wq.y; wv[j][2] = wq.z; wv[j][3] = wq.w;
            }
            for (int r = 0; r < 4; r++)
                for (int j = 0; j < 4; j++)
                    for (int c = 0; c < 4; c++)
                        acc[r][c] += a[r][j] * wv[j][c];
        }
    }
    for (int r = 0; r < 4; r++) {
        float di = dinv[row0 + r0 + r];
        float4 o = {di * acc[r][0], di * acc[r][1], di * acc[r][2], di * acc[r][3]};
        *(float4*)(H + (row0 + r0 + r) * 128 + c0) = o;
    }
}

// H[N x 64] = dinv[row] * (X[N x 128] @ W[128 x 64]); grid = N/32 blocks.
__global__ __launch_bounds__(256) void k_gemm64(const float* __restrict__ X,
                                                const float* __restrict__ W,
                                                const float* __restrict__ dinv,
                                                float* __restrict__ H) {
    __shared__ float Wl[32 * 64];  // 8 KB
    __shared__ float Xs[32 * 32];  // 4 KB
    int t = threadIdx.x;
    size_t row0 = (size_t)blockIdx.x * 32;
    int r0 = (t >> 4) * 2;   // 16 row groups x 2 rows
    int c0 = (t & 15) * 4;   // 16 col groups x 4 cols
    int lr = t >> 3, lk = (t & 7) * 4;
    float acc[2][4] = {};
    for (int kc = 0; kc < 128; kc += 32) {
        __syncthreads();
        ((float4*)Wl)[t]       = ((const float4*)W)[kc * 16 + t];
        ((float4*)Wl)[t + 256] = ((const float4*)W)[kc * 16 + t + 256];
        *(float4*)(Xs + lr * 32 + lk) =
            *(const float4*)(X + (row0 + lr) * 128 + kc + lk);
        __syncthreads();
        for (int kk = 0; kk < 32; kk += 4) {
            float a[2][4], wv[4][4];
            for (int r = 0; r < 2; r++) {
                float4 av = *(const float4*)(Xs + (r0 + r) * 32 + kk);
                a[r][0] = av.x; a[r][1] = av.y; a[r][2] = av.z; a[r][3] = av.w;
            }
            for (int j = 0; j < 4; j++) {
                float4 wq = *(const float4*)(Wl + (kk + j) * 64 + c0);
                wv[j][0] = wq.x; wv[j][1] = wq.y; wv[j][2] = wq.z; wv[j][3] = wq.w;
            }
            for (int r = 0; r < 2; r++)
                for (int j = 0; j < 4; j++)
                    for (int c = 0; c < 4; c++)
                        acc[r][c] += a[r][j] * wv[j][c];
        }
    }
    for (int r = 0; r < 2; r++) {
        float di = dinv[row0 + r0 + r];
        float4 o = {di * acc[r][0], di * acc[r][1], di * acc[r][2], di * acc[r][3]};
        *(float4*)(H + (row0 + r0 + r) * 64 + c0) = o;
    }
}

// ---------------- Pull-mode aggregation: one wave per node, MLP-unrolled ----------

// hs rows are pre-scaled by dinv[row]. out_i = relu(di*(Σ_nbr hs_j + hs_i) + b).
__global__ __launch_bounds__(256) void k_agg_relu(const float* __restrict__ hs,
                                                  const float* __restrict__ dinv,
                                                  const int* __restrict__ row_ptr,
                                                  const int* __restrict__ col,
                                                  const float* __restrict__ bias,
                                                  float* __restrict__ out, int n) {
    int node = blockIdx.x * 4 + (threadIdx.x >> 6);
    if (node >= n) return;
    int lane = threadIdx.x & 63;
    const float2* hp = (const float2*)hs;
    float2 self = hp[(size_t)node * 64 + lane];  // = di * h_i
    float ax = self.x, ay = self.y;
    int p0 = row_ptr[node], p1 = row_ptr[node + 1];
    for (int base = p0; base < p1; base += 64) {
        int nb = min(64, p1 - base);
        int myc = col[base + min(lane, nb - 1)];  // lane-parallel index prefetch
        int k = 0;
        for (; k + 4 <= nb; k += 4) {
            int j0 = __shfl(myc, k);
            int j1 = __shfl(myc, k + 1);
            int j2 = __shfl(myc, k + 2);
            int j3 = __shfl(myc, k + 3);
            float2 v0 = hp[(size_t)j0 * 64 + lane];
            float2 v1 = hp[(size_t)j1 * 64 + lane];
            float2 v2 = hp[(size_t)j2 * 64 + lane];
            float2 v3 = hp[(size_t)j3 * 64 + lane];
            ax += (v0.x + v1.x) + (v2.x + v3.x);
            ay += (v0.y + v1.y) + (v2.y + v3.y);
        }
        for (; k < nb; ++k) {
            int j = __shfl(myc, k);
            float2 v = hp[(size_t)j * 64 + lane];
            ax += v.x;
            ay += v.y;
        }
    }
    float di = dinv[node];
    ax = fmaf(di, ax, bias[2 * lane]);
    ay = fmaf(di, ay, bias[2 * lane + 1]);
    ax = ax > 0.f ? ax : 0.f;
    ay = ay > 0.f ? ay : 0.f;
    float2 o = {ax, ay};
    ((float2*)out)[(size_t)node * 64 + lane] = o;
}

// 64 cols, lane = col. hs pre-scaled. Fused log_softmax across the wave.
__global__ __launch_bounds__(256) void k_agg_lsm(const float* __restrict__ hs,
                                                 const float* __restrict__ dinv,
                                                 const int* __restrict__ row_ptr,
                                                 const int* __restrict__ col,
                                                 const float* __restrict__ bias,
                                                 float* __restrict__ out, int n) {
    int node = blockIdx.x * 4 + (threadIdx.x >> 6);
    if (node >= n) return;
    int lane = threadIdx.x & 63;
    float acc = hs[(size_t)node * 64 + lane];  // self term
    int p0 = row_ptr[node], p1 = row_ptr[node + 1];
    for (int base = p0; base < p1; base += 64) {
        int nb = min(64, p1 - base);
        int myc = col[base + min(lane, nb - 1)];
        int k = 0;
        for (; k + 4 <= nb; k += 4) {
            int j0 = __shfl(myc, k);
            int j1 = __shfl(myc, k + 1);
            int j2 = __shfl(myc, k + 2);
            int j3 = __shfl(myc, k + 3);
            float v0 = hs[(size_t)j0 * 64 + lane];
            float v1 = hs[(size_t)j1 * 64 + lane];
            float v2 = hs[(size_t)j2 * 64 + lane];
            float v3 = hs[(size_t)j3 * 64 + lane];
            acc += (v0 + v1) + (v2 + v3);
        }
        for (; k < nb; ++k) {
            int j = __shfl(myc, k);
            acc += hs[(size_t)j * 64 + lane];
        }
    }
    float v = fmaf(dinv[node], acc, bias[lane]);
    float m = v;
    for (int off = 32; off; off >>= 1) m = fmaxf(m, __shfl_xor(m, off));
    float e = __expf(v - m);
    float s = e;
    for (int off = 32; off; off >>= 1) s += __shfl_xor(s, off);
    out[(size_t)node * 64 + lane] = v - m - __logf(s);
}

// ---------------- launcher ----------------

extern "C" void kernel_launch(void* const* d_in, const int* in_sizes, int n_in,
                              void* d_out, int out_size, void* d_ws, size_t ws_size,
                              hipStream_t stream) {
    const float* x  = (const float*)d_in[0];
    const int*   ei = (const int*)d_in[1];
    const float* W1 = (const float*)d_in[2];
    const float* b1 = (const float*)d_in[3];
    const float* W2 = (const float*)d_in[4];
    const float* b2 = (const float*)d_in[5];
    float* out = (float*)d_out;

    const int N = in_sizes[0] / 128;   // 100000
    const int E = in_sizes[1] / 2;     // 1600000
    const int* src = ei;       // edge_index[0]
    const int* dst = ei + E;   // edge_index[1]

    // workspace carve (256B aligned)
    char* w = (char*)d_ws;
    size_t off = 0;
    auto alloc = [&](size_t bytes) -> void* {
        void* p = w + off;
        off += (bytes + 255) & ~(size_t)255;
        return p;
    };
    int*   indeg    = (int*)alloc((size_t)N * 4);
    int*   row_ptr  = (int*)alloc((size_t)(N + 1) * 4);
    int*   cursor   = (int*)alloc((size_t)N * 4);
    int*   colarr   = (int*)alloc((size_t)E * 4);
    int*   partials = (int*)alloc(256 * 4);
    float* dinv     = (float*)alloc((size_t)N * 4);
    float* h1s      = (float*)alloc((size_t)N * 128 * 4);  // dinv-scaled X@W1
    float* a1       = (float*)alloc((size_t)N * 128 * 4);  // relu layer-1 out
    float* h2s      = (float*)alloc((size_t)N * 64 * 4);   // dinv-scaled a1@W2
    (void)ws_size; (void)n_in; (void)out_size;

    int nscan = (N + 1023) / 1024;  // 98 <= 256
    int npp = (N + NPART - 1) / NPART;  // nodes per XCD partition

    k_zero<<<(N + 255) / 256, 256, 0, stream>>>(indeg, N);
    k_hist_x<<<1024, 256, 0, stream>>>(dst, indeg, E, npp, N);
    k_scan_local<<<nscan, 256, 0, stream>>>(indeg, row_ptr, partials, N);
    k_scan_partials<<<1, 256, 0, stream>>>(partials, nscan);
    k_finalize<<<(N + 255) / 256, 256, 0, stream>>>(row_ptr, partials, indeg, cursor,
                                                    dinv, N, E);
    k_fill_x<<<1024, 256, 0, stream>>>(src, dst, cursor, colarr, E, npp, N);

    k_gemm128<<<N / 32, 256, 0, stream>>>(x, W1, dinv, h1s);
    k_agg_relu<<<(N + 3) / 4, 256, 0, stream>>>(h1s, dinv, row_ptr, colarr, b1, a1, N);
    k_gemm64<<<N / 32, 256, 0, stream>>>(a1, W2, dinv, h2s);
    k_agg_lsm<<<(N + 3) / 4, 256, 0, stream>>>(h2s, dinv, row_ptr, colarr, b2, out, N);
}

// Round 4
// 442.086 us; speedup vs baseline: 1.5708x; 1.1386x over previous
//
#include <hip/hip_runtime.h>
#include <cstdint>
#include <cstddef>

// ---------------- bf16 pack/unpack helpers (RNE) ----------------

__device__ inline unsigned pack_bf16x2(float a, float b) {
    unsigned ua = __float_as_uint(a);
    unsigned ub = __float_as_uint(b);
    ua += 0x7fffu + ((ua >> 16) & 1u);
    ub += 0x7fffu + ((ub >> 16) & 1u);
    return (ua >> 16) | (ub & 0xffff0000u);
}
__device__ inline float bf16lo(unsigned u) { return __uint_as_float(u << 16); }
__device__ inline float bf16hi(unsigned u) { return __uint_as_float(u & 0xffff0000u); }

// ---------------- CSR build (XCD-partitioned) ----------------

#define NPART 8

__global__ void k_zero(int* __restrict__ p, int n) {
    int i = blockIdx.x * blockDim.x + threadIdx.x;
    if (i < n) p[i] = 0;
}

__global__ __launch_bounds__(256) void k_hist_x(const int* __restrict__ dst,
                                                int* __restrict__ indeg,
                                                int E, int npp, int N) {
    int part = blockIdx.x & (NPART - 1);
    int rep  = blockIdx.x >> 3;
    int nrep = gridDim.x >> 3;
    int lo = part * npp;
    int hi = min(N, lo + npp);
    int t = rep * blockDim.x + threadIdx.x;
    int stride = nrep * blockDim.x;
    int E4 = E >> 2;
    const int4* d4 = (const int4*)dst;
    for (int i = t; i < E4; i += stride) {
        int4 d = d4[i];
        if (d.x >= lo && d.x < hi) atomicAdd(&indeg[d.x], 1);
        if (d.y >= lo && d.y < hi) atomicAdd(&indeg[d.y], 1);
        if (d.z >= lo && d.z < hi) atomicAdd(&indeg[d.z], 1);
        if (d.w >= lo && d.w < hi) atomicAdd(&indeg[d.w], 1);
    }
    for (int e = E4 * 4 + t; e < E; e += stride) {
        int d = dst[e];
        if (d >= lo && d < hi) atomicAdd(&indeg[d], 1);
    }
}

__global__ void k_scan_local(const int* __restrict__ in, int* __restrict__ out,
                             int* __restrict__ partials, int n) {
    __shared__ int s[256];
    int t = threadIdx.x;
    int base = blockIdx.x * 1024 + t * 4;
    int v0 = (base + 0) < n ? in[base + 0] : 0;
    int v1 = (base + 1) < n ? in[base + 1] : 0;
    int v2 = (base + 2) < n ? in[base + 2] : 0;
    int v3 = (base + 3) < n ? in[base + 3] : 0;
    int sum = v0 + v1 + v2 + v3;
    s[t] = sum;
    __syncthreads();
    for (int off = 1; off < 256; off <<= 1) {
        int x = (t >= off) ? s[t - off] : 0;
        __syncthreads();
        s[t] += x;
        __syncthreads();
    }
    int excl = s[t] - sum;
    if ((base + 0) < n) out[base + 0] = excl;
    if ((base + 1) < n) out[base + 1] = excl + v0;
    if ((base + 2) < n) out[base + 2] = excl + v0 + v1;
    if ((base + 3) < n) out[base + 3] = excl + v0 + v1 + v2;
    if (t == 255) partials[blockIdx.x] = s[255];
}

__global__ void k_scan_partials(int* __restrict__ partials, int np) {
    __shared__ int s[256];
    int t = threadIdx.x;
    int v = (t < np) ? partials[t] : 0;
    s[t] = v;
    __syncthreads();
    for (int off = 1; off < 256; off <<= 1) {
        int x = (t >= off) ? s[t - off] : 0;
        __syncthreads();
        s[t] += x;
        __syncthreads();
    }
    if (t < np) partials[t] = s[t] - v;
}

__global__ void k_finalize(int* __restrict__ row_ptr, const int* __restrict__ partials,
                           const int* __restrict__ indeg, int* __restrict__ cursor,
                           float* __restrict__ dinv, int n, int E) {
    int i = blockIdx.x * blockDim.x + threadIdx.x;
    if (i < n) {
        int rp = row_ptr[i] + partials[i >> 10];
        row_ptr[i] = rp;
        cursor[i] = rp;
        dinv[i] = rsqrtf((float)indeg[i] + 1.0f);  // +1 = self loop
        if (i == 0) row_ptr[n] = E;
    }
}

__global__ __launch_bounds__(256) void k_fill_x(const int* __restrict__ src,
                                                const int* __restrict__ dst,
                                                int* __restrict__ cursor,
                                                int* __restrict__ col,
                                                int E, int npp, int N) {
    int part = blockIdx.x & (NPART - 1);
    int rep  = blockIdx.x >> 3;
    int nrep = gridDim.x >> 3;
    int lo = part * npp;
    int hi = min(N, lo + npp);
    int t = rep * blockDim.x + threadIdx.x;
    int stride = nrep * blockDim.x;
    int E4 = E >> 2;
    const int4* d4 = (const int4*)dst;
    const int4* s4 = (const int4*)src;
    for (int i = t; i < E4; i += stride) {
        int4 d = d4[i];
        int4 s = s4[i];
        if (d.x >= lo && d.x < hi) { int p = atomicAdd(&cursor[d.x], 1); col[p] = s.x; }
        if (d.y >= lo && d.y < hi) { int p = atomicAdd(&cursor[d.y], 1); col[p] = s.y; }
        if (d.z >= lo && d.z < hi) { int p = atomicAdd(&cursor[d.z], 1); col[p] = s.z; }
        if (d.w >= lo && d.w < hi) { int p = atomicAdd(&cursor[d.w], 1); col[p] = s.w; }
    }
    for (int e = E4 * 4 + t; e < E; e += stride) {
        int d = dst[e];
        if (d >= lo && d < hi) { int p = atomicAdd(&cursor[d], 1); col[p] = src[e]; }
    }
}

// ---------------- GEMMs (fp32 VALU) — epilogue: row *= dinv[row], store bf16 -----

// Hb[N x 64 uints] = bf16x2( dinv[row] * (X @ W1) ); grid = N/32 blocks.
__global__ __launch_bounds__(256) void k_gemm128(const float* __restrict__ X,
                                                 const float* __restrict__ W,
                                                 const float* __restrict__ dinv,
                                                 unsigned* __restrict__ Hb) {
    __shared__ float Wl[32 * 128];  // 16 KB k-chunk of W
    __shared__ float Xs[32 * 32];   // 4 KB  x tile
    int t = threadIdx.x;
    size_t row0 = (size_t)blockIdx.x * 32;
    int r0 = (t >> 5) * 4;   // 8 row groups x 4 rows
    int c0 = (t & 31) * 4;   // 32 col groups x 4 cols
    int lr = t >> 3, lk = (t & 7) * 4;
    float acc[4][4] = {};
    for (int kc = 0; kc < 128; kc += 32) {
        __syncthreads();
        for (int idx = t; idx < 1024; idx += 256)
            ((float4*)Wl)[idx] = ((const float4*)W)[kc * 32 + idx];
        *(float4*)(Xs + lr * 32 + lk) =
            *(const float4*)(X + (row0 + lr) * 128 + kc + lk);
        __syncthreads();
        for (int kk = 0; kk < 32; kk += 4) {
            float a[4][4], wv[4][4];
            for (int r = 0; r < 4; r++) {
                float4 av = *(const float4*)(Xs + (r0 + r) * 32 + kk);
                a[r][0] = av.x; a[r][1] = av.y; a[r][2] = av.z; a[r][3] = av.w;
            }
            for (int j = 0; j < 4; j++) {
                float4 wq = *(const float4*)(Wl + (kk + j) * 128 + c0);
                wv[j][0] = wq.x; wv[j][1] = wq.y; wv[j][2] = wq.z; wv[j][3] = wq.w;
            }
            for (int r = 0; r < 4; r++)
                for (int j = 0; j < 4; j++)
                    for (int c = 0; c < 4; c++)
                        acc[r][c] += a[r][j] * wv[j][c];
        }
    }
    for (int r = 0; r < 4; r++) {
        float di = dinv[row0 + r0 + r];
        uint2 o = {pack_bf16x2(di * acc[r][0], di * acc[r][1]),
                   pack_bf16x2(di * acc[r][2], di * acc[r][3])};
        *(uint2*)(Hb + (row0 + r0 + r) * 64 + (c0 >> 1)) = o;
    }
}

// Hb[N x 32 uints] = bf16x2( dinv[row] * (X @ W2) ); grid = N/32 blocks.
__global__ __launch_bounds__(256) void k_gemm64(const float* __restrict__ X,
                                                const float* __restrict__ W,
                                                const float* __restrict__ dinv,
                                                unsigned* __restrict__ Hb) {
    __shared__ float Wl[32 * 64];  // 8 KB
    __shared__ float Xs[32 * 32];  // 4 KB
    int t = threadIdx.x;
    size_t row0 = (size_t)blockIdx.x * 32;
    int r0 = (t >> 4) * 2;   // 16 row groups x 2 rows
    int c0 = (t & 15) * 4;   // 16 col groups x 4 cols
    int lr = t >> 3, lk = (t & 7) * 4;
    float acc[2][4] = {};
    for (int kc = 0; kc < 128; kc += 32) {
        __syncthreads();
        ((float4*)Wl)[t]       = ((const float4*)W)[kc * 16 + t];
        ((float4*)Wl)[t + 256] = ((const float4*)W)[kc * 16 + t + 256];
        *(float4*)(Xs + lr * 32 + lk) =
            *(const float4*)(X + (row0 + lr) * 128 + kc + lk);
        __syncthreads();
        for (int kk = 0; kk < 32; kk += 4) {
            float a[2][4], wv[4][4];
            for (int r = 0; r < 2; r++) {
                float4 av = *(const float4*)(Xs + (r0 + r) * 32 + kk);
                a[r][0] = av.x; a[r][1] = av.y; a[r][2] = av.z; a[r][3] = av.w;
            }
            for (int j = 0; j < 4; j++) {
                float4 wq = *(const float4*)(Wl + (kk + j) * 64 + c0);
                wv[j][0] = wq.x; wv[j][1] = wq.y; wv[j][2] = wq.z; wv[j][3] = wq.w;
            }
            for (int r = 0; r < 2; r++)
                for (int j = 0; j < 4; j++)
                    for (int c = 0; c < 4; c++)
                        acc[r][c] += a[r][j] * wv[j][c];
        }
    }
    for (int r = 0; r < 2; r++) {
        float di = dinv[row0 + r0 + r];
        uint2 o = {pack_bf16x2(di * acc[r][0], di * acc[r][1]),
                   pack_bf16x2(di * acc[r][2], di * acc[r][3])};
        *(uint2*)(Hb + (row0 + r0 + r) * 32 + (c0 >> 1)) = o;
    }
}

// ---------------- Pull-mode aggregation (bf16 payload, fp32 accumulate) ----------

// hs rows: 64 uints = 128 bf16, pre-scaled by dinv. out = relu(di*Σ + b), fp32.
__global__ __launch_bounds__(256) void k_agg_relu(const unsigned* __restrict__ hs,
                                                  const float* __restrict__ dinv,
                                                  const int* __restrict__ row_ptr,
                                                  const int* __restrict__ col,
                                                  const float* __restrict__ bias,
                                                  float* __restrict__ out, int n) {
    int node = blockIdx.x * 4 + (threadIdx.x >> 6);
    if (node >= n) return;
    int lane = threadIdx.x & 63;
    unsigned su = hs[(size_t)node * 64 + lane];  // self term (pre-scaled)
    float ax = bf16lo(su), ay = bf16hi(su);
    int p0 = row_ptr[node], p1 = row_ptr[node + 1];
    for (int base = p0; base < p1; base += 64) {
        int nb = min(64, p1 - base);
        int myc = col[base + min(lane, nb - 1)];  // lane-parallel index prefetch
        int k = 0;
        for (; k + 4 <= nb; k += 4) {
            int j0 = __shfl(myc, k);
            int j1 = __shfl(myc, k + 1);
            int j2 = __shfl(myc, k + 2);
            int j3 = __shfl(myc, k + 3);
            unsigned v0 = hs[(size_t)j0 * 64 + lane];
            unsigned v1 = hs[(size_t)j1 * 64 + lane];
            unsigned v2 = hs[(size_t)j2 * 64 + lane];
            unsigned v3 = hs[(size_t)j3 * 64 + lane];
            ax += (bf16lo(v0) + bf16lo(v1)) + (bf16lo(v2) + bf16lo(v3));
            ay += (bf16hi(v0) + bf16hi(v1)) + (bf16hi(v2) + bf16hi(v3));
        }
        for (; k < nb; ++k) {
            int j = __shfl(myc, k);
            unsigned v = hs[(size_t)j * 64 + lane];
            ax += bf16lo(v);
            ay += bf16hi(v);
        }
    }
    float di = dinv[node];
    ax = fmaf(di, ax, bias[2 * lane]);
    ay = fmaf(di, ay, bias[2 * lane + 1]);
    ax = ax > 0.f ? ax : 0.f;
    ay = ay > 0.f ? ay : 0.f;
    float2 o = {ax, ay};
    ((float2*)out)[(size_t)node * 64 + lane] = o;
}

// hs rows: 64 bf16 (as ushort), lane = col. Fused log_softmax across the wave.
__global__ __launch_bounds__(256) void k_agg_lsm(const unsigned short* __restrict__ hs,
                                                 const float* __restrict__ dinv,
                                                 const int* __restrict__ row_ptr,
                                                 const int* __restrict__ col,
                                                 const float* __restrict__ bias,
                                                 float* __restrict__ out, int n) {
    int node = blockIdx.x * 4 + (threadIdx.x >> 6);
    if (node >= n) return;
    int lane = threadIdx.x & 63;
    float acc = __uint_as_float(((unsigned)hs[(size_t)node * 64 + lane]) << 16);
    int p0 = row_ptr[node], p1 = row_ptr[node + 1];
    for (int base = p0; base < p1; base += 64) {
        int nb = min(64, p1 - base);
        int myc = col[base + min(lane, nb - 1)];
        int k = 0;
        for (; k + 4 <= nb; k += 4) {
            int j0 = __shfl(myc, k);
            int j1 = __shfl(myc, k + 1);
            int j2 = __shfl(myc, k + 2);
            int j3 = __shfl(myc, k + 3);
            float v0 = __uint_as_float(((unsigned)hs[(size_t)j0 * 64 + lane]) << 16);
            float v1 = __uint_as_float(((unsigned)hs[(size_t)j1 * 64 + lane]) << 16);
            float v2 = __uint_as_float(((unsigned)hs[(size_t)j2 * 64 + lane]) << 16);
            float v3 = __uint_as_float(((unsigned)hs[(size_t)j3 * 64 + lane]) << 16);
            acc += (v0 + v1) + (v2 + v3);
        }
        for (; k < nb; ++k) {
            int j = __shfl(myc, k);
            acc += __uint_as_float(((unsigned)hs[(size_t)j * 64 + lane]) << 16);
        }
    }
    float v = fmaf(dinv[node], acc, bias[lane]);
    float m = v;
    for (int off = 32; off; off >>= 1) m = fmaxf(m, __shfl_xor(m, off));
    float e = __expf(v - m);
    float s = e;
    for (int off = 32; off; off >>= 1) s += __shfl_xor(s, off);
    out[(size_t)node * 64 + lane] = v - m - __logf(s);
}

// ---------------- launcher ----------------

extern "C" void kernel_launch(void* const* d_in, const int* in_sizes, int n_in,
                              void* d_out, int out_size, void* d_ws, size_t ws_size,
                              hipStream_t stream) {
    const float* x  = (const float*)d_in[0];
    const int*   ei = (const int*)d_in[1];
    const float* W1 = (const float*)d_in[2];
    const float* b1 = (const float*)d_in[3];
    const float* W2 = (const float*)d_in[4];
    const float* b2 = (const float*)d_in[5];
    float* out = (float*)d_out;

    const int N = in_sizes[0] / 128;   // 100000
    const int E = in_sizes[1] / 2;     // 1600000
    const int* src = ei;       // edge_index[0]
    const int* dst = ei + E;   // edge_index[1]

    // workspace carve (256B aligned)
    char* w = (char*)d_ws;
    size_t off = 0;
    auto alloc = [&](size_t bytes) -> void* {
        void* p = w + off;
        off += (bytes + 255) & ~(size_t)255;
        return p;
    };
    int*      indeg    = (int*)alloc((size_t)N * 4);
    int*      row_ptr  = (int*)alloc((size_t)(N + 1) * 4);
    int*      cursor   = (int*)alloc((size_t)N * 4);
    int*      colarr   = (int*)alloc((size_t)E * 4);
    int*      partials = (int*)alloc(256 * 4);
    float*    dinv     = (float*)alloc((size_t)N * 4);
    unsigned* h1b      = (unsigned*)alloc((size_t)N * 64 * 4);  // bf16 dinv-scaled X@W1
    float*    a1       = (float*)alloc((size_t)N * 128 * 4);    // relu layer-1 out fp32
    unsigned* h2b      = (unsigned*)alloc((size_t)N * 32 * 4);  // bf16 dinv-scaled a1@W2
    (void)ws_size; (void)n_in; (void)out_size;

    int nscan = (N + 1023) / 1024;  // 98 <= 256
    int npp = (N + NPART - 1) / NPART;  // nodes per XCD partition

    k_zero<<<(N + 255) / 256, 256, 0, stream>>>(indeg, N);
    k_hist_x<<<1024, 256, 0, stream>>>(dst, indeg, E, npp, N);
    k_scan_local<<<nscan, 256, 0, stream>>>(indeg, row_ptr, partials, N);
    k_scan_partials<<<1, 256, 0, stream>>>(partials, nscan);
    k_finalize<<<(N + 255) / 256, 256, 0, stream>>>(row_ptr, partials, indeg, cursor,
                                                    dinv, N, E);
    k_fill_x<<<1024, 256, 0, stream>>>(src, dst, cursor, colarr, E, npp, N);

    k_gemm128<<<N / 32, 256, 0, stream>>>(x, W1, dinv, h1b);
    k_agg_relu<<<(N + 3) / 4, 256, 0, stream>>>(h1b, dinv, row_ptr, colarr, b1, a1, N);
    k_gemm64<<<N / 32, 256, 0, stream>>>(a1, W2, dinv, h2b);
    k_agg_lsm<<<(N + 3) / 4, 256, 0, stream>>>((const unsigned short*)h2b, dinv,
                                               row_ptr, colarr, b2, out, N);
}

// Round 5
// 440.092 us; speedup vs baseline: 1.5780x; 1.0045x over previous
//
#include <hip/hip_runtime.h>
#include <cstdint>
#include <cstddef>

// ---------------- bf16 pack/unpack helpers (RNE) ----------------

__device__ inline unsigned pack_bf16x2(float a, float b) {
    unsigned ua = __float_as_uint(a);
    unsigned ub = __float_as_uint(b);
    ua += 0x7fffu + ((ua >> 16) & 1u);
    ub += 0x7fffu + ((ub >> 16) & 1u);
    return (ua >> 16) | (ub & 0xffff0000u);
}
__device__ inline float bf16lo(unsigned u) { return __uint_as_float(u << 16); }
__device__ inline float bf16hi(unsigned u) { return __uint_as_float(u & 0xffff0000u); }

typedef int iv4 __attribute__((ext_vector_type(4)));

// ---------------- CSR build (XCD-partitioned + nt streaming loads) ----------------

#define NPART 8

__global__ void k_zero(int* __restrict__ p, int n) {
    int i = blockIdx.x * blockDim.x + threadIdx.x;
    if (i < n) p[i] = 0;
}

__global__ __launch_bounds__(256) void k_hist_x(const int* __restrict__ dst,
                                                int* __restrict__ indeg,
                                                int E, int npp, int N) {
    int part = blockIdx.x & (NPART - 1);
    int rep  = blockIdx.x >> 3;
    int nrep = gridDim.x >> 3;
    int lo = part * npp;
    int hi = min(N, lo + npp);
    int t = rep * blockDim.x + threadIdx.x;
    int stride = nrep * blockDim.x;
    int E4 = E >> 2;
    const iv4* d4 = (const iv4*)dst;
    for (int i = t; i < E4; i += stride) {
        iv4 d = __builtin_nontemporal_load(d4 + i);  // stream: don't pollute L2
        if (d.x >= lo && d.x < hi) atomicAdd(&indeg[d.x], 1);
        if (d.y >= lo && d.y < hi) atomicAdd(&indeg[d.y], 1);
        if (d.z >= lo && d.z < hi) atomicAdd(&indeg[d.z], 1);
        if (d.w >= lo && d.w < hi) atomicAdd(&indeg[d.w], 1);
    }
    for (int e = E4 * 4 + t; e < E; e += stride) {
        int d = __builtin_nontemporal_load(dst + e);
        if (d >= lo && d < hi) atomicAdd(&indeg[d], 1);
    }
}

__global__ void k_scan_local(const int* __restrict__ in, int* __restrict__ out,
                             int* __restrict__ partials, int n) {
    __shared__ int s[256];
    int t = threadIdx.x;
    int base = blockIdx.x * 1024 + t * 4;
    int v0 = (base + 0) < n ? in[base + 0] : 0;
    int v1 = (base + 1) < n ? in[base + 1] : 0;
    int v2 = (base + 2) < n ? in[base + 2] : 0;
    int v3 = (base + 3) < n ? in[base + 3] : 0;
    int sum = v0 + v1 + v2 + v3;
    s[t] = sum;
    __syncthreads();
    for (int off = 1; off < 256; off <<= 1) {
        int x = (t >= off) ? s[t - off] : 0;
        __syncthreads();
        s[t] += x;
        __syncthreads();
    }
    int excl = s[t] - sum;
    if ((base + 0) < n) out[base + 0] = excl;
    if ((base + 1) < n) out[base + 1] = excl + v0;
    if ((base + 2) < n) out[base + 2] = excl + v0 + v1;
    if ((base + 3) < n) out[base + 3] = excl + v0 + v1 + v2;
    if (t == 255) partials[blockIdx.x] = s[255];
}

__global__ void k_scan_partials(int* __restrict__ partials, int np) {
    __shared__ int s[256];
    int t = threadIdx.x;
    int v = (t < np) ? partials[t] : 0;
    s[t] = v;
    __syncthreads();
    for (int off = 1; off < 256; off <<= 1) {
        int x = (t >= off) ? s[t - off] : 0;
        __syncthreads();
        s[t] += x;
        __syncthreads();
    }
    if (t < np) partials[t] = s[t] - v;
}

__global__ void k_finalize(int* __restrict__ row_ptr, const int* __restrict__ partials,
                           const int* __restrict__ indeg, int* __restrict__ cursor,
                           float* __restrict__ dinv, int n, int E) {
    int i = blockIdx.x * blockDim.x + threadIdx.x;
    if (i < n) {
        int rp = row_ptr[i] + partials[i >> 10];
        row_ptr[i] = rp;
        cursor[i] = rp;
        dinv[i] = rsqrtf((float)indeg[i] + 1.0f);  // +1 = self loop
        if (i == 0) row_ptr[n] = E;
    }
}

__global__ __launch_bounds__(256) void k_fill_x(const int* __restrict__ src,
                                                const int* __restrict__ dst,
                                                int* __restrict__ cursor,
                                                int* __restrict__ col,
                                                int E, int npp, int N) {
    int part = blockIdx.x & (NPART - 1);
    int rep  = blockIdx.x >> 3;
    int nrep = gridDim.x >> 3;
    int lo = part * npp;
    int hi = min(N, lo + npp);
    int t = rep * blockDim.x + threadIdx.x;
    int stride = nrep * blockDim.x;
    int E4 = E >> 2;
    const iv4* d4 = (const iv4*)dst;
    const iv4* s4 = (const iv4*)src;
    for (int i = t; i < E4; i += stride) {
        iv4 d = __builtin_nontemporal_load(d4 + i);  // stream
        bool mx = d.x >= lo && d.x < hi;
        bool my = d.y >= lo && d.y < hi;
        bool mz = d.z >= lo && d.z < hi;
        bool mw = d.w >= lo && d.w < hi;
        if (mx | my | mz | mw) {  // skip src load when no lane of this int4 matches
            iv4 s = __builtin_nontemporal_load(s4 + i);
            if (mx) { int p = atomicAdd(&cursor[d.x], 1); col[p] = s.x; }
            if (my) { int p = atomicAdd(&cursor[d.y], 1); col[p] = s.y; }
            if (mz) { int p = atomicAdd(&cursor[d.z], 1); col[p] = s.z; }
            if (mw) { int p = atomicAdd(&cursor[d.w], 1); col[p] = s.w; }
        }
    }
    for (int e = E4 * 4 + t; e < E; e += stride) {
        int d = __builtin_nontemporal_load(dst + e);
        if (d >= lo && d < hi) {
            int p = atomicAdd(&cursor[d], 1);
            col[p] = __builtin_nontemporal_load(src + e);
        }
    }
}

// ---------------- GEMMs (fp32 VALU) — epilogue: row *= dinv[row], store bf16 -----

// Hb[N x 64 uints] = bf16x2( dinv[row] * (X @ W1) ); grid = N/32 blocks.
__global__ __launch_bounds__(256) void k_gemm128(const float* __restrict__ X,
                                                 const float* __restrict__ W,
                                                 const float* __restrict__ dinv,
                                                 unsigned* __restrict__ Hb) {
    __shared__ float Wl[32 * 128];  // 16 KB k-chunk of W
    __shared__ float Xs[32 * 32];   // 4 KB  x tile
    int t = threadIdx.x;
    size_t row0 = (size_t)blockIdx.x * 32;
    int r0 = (t >> 5) * 4;   // 8 row groups x 4 rows
    int c0 = (t & 31) * 4;   // 32 col groups x 4 cols
    int lr = t >> 3, lk = (t & 7) * 4;
    float acc[4][4] = {};
    for (int kc = 0; kc < 128; kc += 32) {
        __syncthreads();
        for (int idx = t; idx < 1024; idx += 256)
            ((float4*)Wl)[idx] = ((const float4*)W)[kc * 32 + idx];
        *(float4*)(Xs + lr * 32 + lk) =
            *(const float4*)(X + (row0 + lr) * 128 + kc + lk);
        __syncthreads();
        for (int kk = 0; kk < 32; kk += 4) {
            float a[4][4], wv[4][4];
            for (int r = 0; r < 4; r++) {
                float4 av = *(const float4*)(Xs + (r0 + r) * 32 + kk);
                a[r][0] = av.x; a[r][1] = av.y; a[r][2] = av.z; a[r][3] = av.w;
            }
            for (int j = 0; j < 4; j++) {
                float4 wq = *(const float4*)(Wl + (kk + j) * 128 + c0);
                wv[j][0] = wq.x; wv[j][1] = wq.y; wv[j][2] = wq.z; wv[j][3] = wq.w;
            }
            for (int r = 0; r < 4; r++)
                for (int j = 0; j < 4; j++)
                    for (int c = 0; c < 4; c++)
                        acc[r][c] += a[r][j] * wv[j][c];
        }
    }
    for (int r = 0; r < 4; r++) {
        float di = dinv[row0 + r0 + r];
        uint2 o = {pack_bf16x2(di * acc[r][0], di * acc[r][1]),
                   pack_bf16x2(di * acc[r][2], di * acc[r][3])};
        *(uint2*)(Hb + (row0 + r0 + r) * 64 + (c0 >> 1)) = o;
    }
}

// Hb[N x 32 uints] = bf16x2( dinv[row] * (X @ W2) ); grid = N/32 blocks.
__global__ __launch_bounds__(256) void k_gemm64(const float* __restrict__ X,
                                                const float* __restrict__ W,
                                                const float* __restrict__ dinv,
                                                unsigned* __restrict__ Hb) {
    __shared__ float Wl[32 * 64];  // 8 KB
    __shared__ float Xs[32 * 32];  // 4 KB
    int t = threadIdx.x;
    size_t row0 = (size_t)blockIdx.x * 32;
    int r0 = (t >> 4) * 2;   // 16 row groups x 2 rows
    int c0 = (t & 15) * 4;   // 16 col groups x 4 cols
    int lr = t >> 3, lk = (t & 7) * 4;
    float acc[2][4] = {};
    for (int kc = 0; kc < 128; kc += 32) {
        __syncthreads();
        ((float4*)Wl)[t]       = ((const float4*)W)[kc * 16 + t];
        ((float4*)Wl)[t + 256] = ((const float4*)W)[kc * 16 + t + 256];
        *(float4*)(Xs + lr * 32 + lk) =
            *(const float4*)(X + (row0 + lr) * 128 + kc + lk);
        __syncthreads();
        for (int kk = 0; kk < 32; kk += 4) {
            float a[2][4], wv[4][4];
            for (int r = 0; r < 2; r++) {
                float4 av = *(const float4*)(Xs + (r0 + r) * 32 + kk);
                a[r][0] = av.x; a[r][1] = av.y; a[r][2] = av.z; a[r][3] = av.w;
            }
            for (int j = 0; j < 4; j++) {
                float4 wq = *(const float4*)(Wl + (kk + j) * 64 + c0);
                wv[j][0] = wq.x; wv[j][1] = wq.y; wv[j][2] = wq.z; wv[j][3] = wq.w;
            }
            for (int r = 0; r < 2; r++)
                for (int j = 0; j < 4; j++)
                    for (int c = 0; c < 4; c++)
                        acc[r][c] += a[r][j] * wv[j][c];
        }
    }
    for (int r = 0; r < 2; r++) {
        float di = dinv[row0 + r0 + r];
        uint2 o = {pack_bf16x2(di * acc[r][0], di * acc[r][1]),
                   pack_bf16x2(di * acc[r][2], di * acc[r][3])};
        *(uint2*)(Hb + (row0 + r0 + r) * 32 + (c0 >> 1)) = o;
    }
}

// ---------------- Pull-mode aggregation (bf16 payload, fp32 accumulate) ----------

// hs rows: 64 uints = 128 bf16, pre-scaled by dinv. out = relu(di*Σ + b), fp32.
__global__ __launch_bounds__(256) void k_agg_relu(const unsigned* __restrict__ hs,
                                                  const float* __restrict__ dinv,
                                                  const int* __restrict__ row_ptr,
                                                  const int* __restrict__ col,
                                                  const float* __restrict__ bias,
                                                  float* __restrict__ out, int n) {
    int node = blockIdx.x * 4 + (threadIdx.x >> 6);
    if (node >= n) return;
    int lane = threadIdx.x & 63;
    unsigned su = hs[(size_t)node * 64 + lane];  // self term (pre-scaled)
    float ax = bf16lo(su), ay = bf16hi(su);
    int p0 = row_ptr[node], p1 = row_ptr[node + 1];
    for (int base = p0; base < p1; base += 64) {
        int nb = min(64, p1 - base);
        int myc = col[base + min(lane, nb - 1)];  // lane-parallel index prefetch
        int k = 0;
        for (; k + 4 <= nb; k += 4) {
            int j0 = __shfl(myc, k);
            int j1 = __shfl(myc, k + 1);
            int j2 = __shfl(myc, k + 2);
            int j3 = __shfl(myc, k + 3);
            unsigned v0 = hs[(size_t)j0 * 64 + lane];
            unsigned v1 = hs[(size_t)j1 * 64 + lane];
            unsigned v2 = hs[(size_t)j2 * 64 + lane];
            unsigned v3 = hs[(size_t)j3 * 64 + lane];
            ax += (bf16lo(v0) + bf16lo(v1)) + (bf16lo(v2) + bf16lo(v3));
            ay += (bf16hi(v0) + bf16hi(v1)) + (bf16hi(v2) + bf16hi(v3));
        }
        for (; k < nb; ++k) {
            int j = __shfl(myc, k);
            unsigned v = hs[(size_t)j * 64 + lane];
            ax += bf16lo(v);
            ay += bf16hi(v);
        }
    }
    float di = dinv[node];
    ax = fmaf(di, ax, bias[2 * lane]);
    ay = fmaf(di, ay, bias[2 * lane + 1]);
    ax = ax > 0.f ? ax : 0.f;
    ay = ay > 0.f ? ay : 0.f;
    float2 o = {ax, ay};
    ((float2*)out)[(size_t)node * 64 + lane] = o;
}

// hs rows: 64 bf16 (as ushort), lane = col. Fused log_softmax across the wave.
__global__ __launch_bounds__(256) void k_agg_lsm(const unsigned short* __restrict__ hs,
                                                 const float* __restrict__ dinv,
                                                 const int* __restrict__ row_ptr,
                                                 const int* __restrict__ col,
                                                 const float* __restrict__ bias,
                                                 float* __restrict__ out, int n) {
    int node = blockIdx.x * 4 + (threadIdx.x >> 6);
    if (node >= n) return;
    int lane = threadIdx.x & 63;
    float acc = __uint_as_float(((unsigned)hs[(size_t)node * 64 + lane]) << 16);
    int p0 = row_ptr[node], p1 = row_ptr[node + 1];
    for (int base = p0; base < p1; base += 64) {
        int nb = min(64, p1 - base);
        int myc = col[base + min(lane, nb - 1)];
        int k = 0;
        for (; k + 4 <= nb; k += 4) {
            int j0 = __shfl(myc, k);
            int j1 = __shfl(myc, k + 1);
            int j2 = __shfl(myc, k + 2);
            int j3 = __shfl(myc, k + 3);
            float v0 = __uint_as_float(((unsigned)hs[(size_t)j0 * 64 + lane]) << 16);
            float v1 = __uint_as_float(((unsigned)hs[(size_t)j1 * 64 + lane]) << 16);
            float v2 = __uint_as_float(((unsigned)hs[(size_t)j2 * 64 + lane]) << 16);
            float v3 = __uint_as_float(((unsigned)hs[(size_t)j3 * 64 + lane]) << 16);
            acc += (v0 + v1) + (v2 + v3);
        }
        for (; k < nb; ++k) {
            int j = __shfl(myc, k);
            acc += __uint_as_float(((unsigned)hs[(size_t)j * 64 + lane]) << 16);
        }
    }
    float v = fmaf(dinv[node], acc, bias[lane]);
    float m = v;
    for (int off = 32; off; off >>= 1) m = fmaxf(m, __shfl_xor(m, off));
    float e = __expf(v - m);
    float s = e;
    for (int off = 32; off; off >>= 1) s += __shfl_xor(s, off);
    out[(size_t)node * 64 + lane] = v - m - __logf(s);
}

// ---------------- launcher ----------------

extern "C" void kernel_launch(void* const* d_in, const int* in_sizes, int n_in,
                              void* d_out, int out_size, void* d_ws, size_t ws_size,
                              hipStream_t stream) {
    const float* x  = (const float*)d_in[0];
    const int*   ei = (const int*)d_in[1];
    const float* W1 = (const float*)d_in[2];
    const float* b1 = (const float*)d_in[3];
    const float* W2 = (const float*)d_in[4];
    const float* b2 = (const float*)d_in[5];
    float* out = (float*)d_out;

    const int N = in_sizes[0] / 128;   // 100000
    const int E = in_sizes[1] / 2;     // 1600000
    const int* src = ei;       // edge_index[0]
    const int* dst = ei + E;   // edge_index[1]

    // workspace carve (256B aligned)
    char* w = (char*)d_ws;
    size_t off = 0;
    auto alloc = [&](size_t bytes) -> void* {
        void* p = w + off;
        off += (bytes + 255) & ~(size_t)255;
        return p;
    };
    int*      indeg    = (int*)alloc((size_t)N * 4);
    int*      row_ptr  = (int*)alloc((size_t)(N + 1) * 4);
    int*      cursor   = (int*)alloc((size_t)N * 4);
    int*      colarr   = (int*)alloc((size_t)E * 4);
    int*      partials = (int*)alloc(256 * 4);
    float*    dinv     = (float*)alloc((size_t)N * 4);
    unsigned* h1b      = (unsigned*)alloc((size_t)N * 64 * 4);  // bf16 dinv-scaled X@W1
    float*    a1       = (float*)alloc((size_t)N * 128 * 4);    // relu layer-1 out fp32
    unsigned* h2b      = (unsigned*)alloc((size_t)N * 32 * 4);  // bf16 dinv-scaled a1@W2
    (void)ws_size; (void)n_in; (void)out_size;

    int nscan = (N + 1023) / 1024;  // 98 <= 256
    int npp = (N + NPART - 1) / NPART;  // nodes per XCD partition

    k_zero<<<(N + 255) / 256, 256, 0, stream>>>(indeg, N);
    k_hist_x<<<1024, 256, 0, stream>>>(dst, indeg, E, npp, N);
    k_scan_local<<<nscan, 256, 0, stream>>>(indeg, row_ptr, partials, N);
    k_scan_partials<<<1, 256, 0, stream>>>(partials, nscan);
    k_finalize<<<(N + 255) / 256, 256, 0, stream>>>(row_ptr, partials, indeg, cursor,
                                                    dinv, N, E);
    k_fill_x<<<1024, 256, 0, stream>>>(src, dst, cursor, colarr, E, npp, N);

    k_gemm128<<<N / 32, 256, 0, stream>>>(x, W1, dinv, h1b);
    k_agg_relu<<<(N + 3) / 4, 256, 0, stream>>>(h1b, dinv, row_ptr, colarr, b1, a1, N);
    k_gemm64<<<N / 32, 256, 0, stream>>>(a1, W2, dinv, h2b);
    k_agg_lsm<<<(N + 3) / 4, 256, 0, stream>>>((const unsigned short*)h2b, dinv,
                                               row_ptr, colarr, b2, out, N);
}

// Round 6
// 356.579 us; speedup vs baseline: 1.9475x; 1.2342x over previous
//
#include <hip/hip_runtime.h>
#include <cstdint>
#include <cstddef>

// ---------------- bf16 pack/unpack helpers (RNE) ----------------

__device__ inline unsigned pack_bf16x2(float a, float b) {
    unsigned ua = __float_as_uint(a);
    unsigned ub = __float_as_uint(b);
    ua += 0x7fffu + ((ua >> 16) & 1u);
    ub += 0x7fffu + ((ub >> 16) & 1u);
    return (ua >> 16) | (ub & 0xffff0000u);
}
__device__ inline float bf16lo(unsigned u) { return __uint_as_float(u << 16); }
__device__ inline float bf16hi(unsigned u) { return __uint_as_float(u & 0xffff0000u); }

typedef int iv4 __attribute__((ext_vector_type(4)));

#define NPART 8      // dst-partitions == XCDs (blockIdx%8 locality heuristic)
#define KB    32     // blocks per partition in count/fill passes
#define NPP_MAX 12500

// ---------------- CSR build: atomic-free counting-sort pipeline ----------------

__global__ void k_zero16(int* __restrict__ p) {
    if (threadIdx.x < 16) p[threadIdx.x] = 0;
}

// A1: global bucket sizes (8 counters). LDS-reduced, 8 global atomics/block.
__global__ __launch_bounds__(256) void k_bcount(const int* __restrict__ dst,
                                                int* __restrict__ bucketCount,
                                                int E, int npp) {
    __shared__ int c8[NPART];
    if (threadIdx.x < NPART) c8[threadIdx.x] = 0;
    __syncthreads();
    int t = blockIdx.x * blockDim.x + threadIdx.x;
    int stride = gridDim.x * blockDim.x;
    int E4 = E >> 2;
    const iv4* d4 = (const iv4*)dst;
    for (int i = t; i < E4; i += stride) {
        iv4 d = d4[i];
        atomicAdd(&c8[(unsigned)d.x / (unsigned)npp], 1);
        atomicAdd(&c8[(unsigned)d.y / (unsigned)npp], 1);
        atomicAdd(&c8[(unsigned)d.z / (unsigned)npp], 1);
        atomicAdd(&c8[(unsigned)d.w / (unsigned)npp], 1);
    }
    for (int e = E4 * 4 + t; e < E; e += stride)
        atomicAdd(&c8[(unsigned)dst[e] / (unsigned)npp], 1);
    __syncthreads();
    if (threadIdx.x < NPART) atomicAdd(&bucketCount[threadIdx.x], c8[threadIdx.x]);
}

// A2: tiny scan: bucketBase = exclusive scan of bucketCount; cursor = base.
__global__ void k_bscan(const int* __restrict__ bucketCount,
                        int* __restrict__ bucketBase,
                        int* __restrict__ bucketCursor) {
    if (threadIdx.x == 0) {
        int run = 0;
        for (int p = 0; p < NPART; ++p) {
            bucketBase[p] = run;
            bucketCursor[p] = run;
            run += bucketCount[p];
        }
    }
}

// A3: scatter edges into per-partition segments as (dst,src) pairs.
// Per chunk: LDS count -> one global reservation per bucket -> LDS-rank replay.
__global__ __launch_bounds__(256) void k_bucket(const int* __restrict__ src,
                                                const int* __restrict__ dst,
                                                int* __restrict__ bucketCursor,
                                                int2* __restrict__ pairs,
                                                int E, int npp) {
    __shared__ int cnt8[NPART], run8[NPART], gbase8[NPART];
    int tid = threadIdx.x;
    int base_e = blockIdx.x * 4096 + tid * 16;
    int nv = min(16, E - base_e);
    if (nv < 0) nv = 0;
    int dv[16], sv[16];
    if (nv == 16) {
        for (int q = 0; q < 4; ++q) {
            iv4 d = *(const iv4*)(dst + base_e + q * 4);
            iv4 s = *(const iv4*)(src + base_e + q * 4);
            dv[q * 4 + 0] = d.x; dv[q * 4 + 1] = d.y; dv[q * 4 + 2] = d.z; dv[q * 4 + 3] = d.w;
            sv[q * 4 + 0] = s.x; sv[q * 4 + 1] = s.y; sv[q * 4 + 2] = s.z; sv[q * 4 + 3] = s.w;
        }
    } else {
        for (int k = 0; k < nv; ++k) { dv[k] = dst[base_e + k]; sv[k] = src[base_e + k]; }
    }
    if (tid < NPART) { cnt8[tid] = 0; run8[tid] = 0; }
    __syncthreads();
    for (int k = 0; k < nv; ++k)
        atomicAdd(&cnt8[(unsigned)dv[k] / (unsigned)npp], 1);
    __syncthreads();
    if (tid < NPART) gbase8[tid] = atomicAdd(&bucketCursor[tid], cnt8[tid]);
    __syncthreads();
    for (int k = 0; k < nv; ++k) {
        int p = (unsigned)dv[k] / (unsigned)npp;
        int r = atomicAdd(&run8[p], 1);
        int2 pr; pr.x = dv[k]; pr.y = sv[k];
        pairs[gbase8[p] + r] = pr;
    }
}

// B: per-(partition,block) LDS histogram of dst over the block's pair sub-chunk;
// flush partial counts with plain stores. cntarr[(p*KB+b)*npp + i].
__global__ __launch_bounds__(256) void k_count_part(const int2* __restrict__ pairs,
                                                    const int* __restrict__ bucketBase,
                                                    const int* __restrict__ bucketCount,
                                                    int* __restrict__ cntarr, int npp) {
    __shared__ int h[NPP_MAX];
    int p = blockIdx.x & (NPART - 1);
    int b = blockIdx.x >> 3;
    int lo = p * npp;
    for (int i = threadIdx.x; i < npp; i += 256) h[i] = 0;
    __syncthreads();
    int segBase = bucketBase[p], sz = bucketCount[p];
    int chunk = (sz + KB - 1) / KB;
    int s0 = segBase + b * chunk;
    int s1 = min(segBase + sz, s0 + chunk);
    for (int i = s0 + threadIdx.x; i < s1; i += 256)
        atomicAdd(&h[pairs[i].x - lo], 1);
    __syncthreads();
    size_t out = (size_t)(p * KB + b) * npp;
    for (int i = threadIdx.x; i < npp; i += 256) cntarr[out + i] = h[i];
}

// C1: indeg[d] = sum over KB blocks of partial counts.
__global__ void k_indeg(const int* __restrict__ cntarr, int* __restrict__ indeg,
                        int n, int npp) {
    int d = blockIdx.x * blockDim.x + threadIdx.x;
    if (d >= n) return;
    int p = (unsigned)d / (unsigned)npp;
    int dl = d - p * npp;
    size_t base = (size_t)p * KB * npp + dl;
    int s = 0;
    for (int b = 0; b < KB; ++b) s += cntarr[base + (size_t)b * npp];
    indeg[d] = s;
}

// (scan pipeline: indeg -> row_ptr)
__global__ void k_scan_local(const int* __restrict__ in, int* __restrict__ out,
                             int* __restrict__ partials, int n) {
    __shared__ int s[256];
    int t = threadIdx.x;
    int base = blockIdx.x * 1024 + t * 4;
    int v0 = (base + 0) < n ? in[base + 0] : 0;
    int v1 = (base + 1) < n ? in[base + 1] : 0;
    int v2 = (base + 2) < n ? in[base + 2] : 0;
    int v3 = (base + 3) < n ? in[base + 3] : 0;
    int sum = v0 + v1 + v2 + v3;
    s[t] = sum;
    __syncthreads();
    for (int off = 1; off < 256; off <<= 1) {
        int x = (t >= off) ? s[t - off] : 0;
        __syncthreads();
        s[t] += x;
        __syncthreads();
    }
    int excl = s[t] - sum;
    if ((base + 0) < n) out[base + 0] = excl;
    if ((base + 1) < n) out[base + 1] = excl + v0;
    if ((base + 2) < n) out[base + 2] = excl + v0 + v1;
    if ((base + 3) < n) out[base + 3] = excl + v0 + v1 + v2;
    if (t == 255) partials[blockIdx.x] = s[255];
}

__global__ void k_scan_partials(int* __restrict__ partials, int np) {
    __shared__ int s[256];
    int t = threadIdx.x;
    int v = (t < np) ? partials[t] : 0;
    s[t] = v;
    __syncthreads();
    for (int off = 1; off < 256; off <<= 1) {
        int x = (t >= off) ? s[t - off] : 0;
        __syncthreads();
        s[t] += x;
        __syncthreads();
    }
    if (t < np) partials[t] = s[t] - v;
}

__global__ void k_finalize(int* __restrict__ row_ptr, const int* __restrict__ partials,
                           const int* __restrict__ indeg, float* __restrict__ dinv,
                           int n, int E) {
    int i = blockIdx.x * blockDim.x + threadIdx.x;
    if (i < n) {
        int rp = row_ptr[i] + partials[i >> 10];
        row_ptr[i] = rp;
        dinv[i] = rsqrtf((float)indeg[i] + 1.0f);  // +1 = self loop
        if (i == 0) row_ptr[n] = E;
    }
}

// C2: in-place convert partial counts -> per-(block,dst) base offsets:
// base[b][d] = row_ptr[d] + sum_{b'<b} cnt[b'][d].
__global__ void k_bases(int* __restrict__ cntarr, const int* __restrict__ row_ptr,
                        int n, int npp) {
    int d = blockIdx.x * blockDim.x + threadIdx.x;
    if (d >= n) return;
    int p = (unsigned)d / (unsigned)npp;
    int dl = d - p * npp;
    size_t base = (size_t)p * KB * npp + dl;
    int run = row_ptr[d];
    for (int b = 0; b < KB; ++b) {
        size_t idx = base + (size_t)b * npp;
        int c = cntarr[idx];
        cntarr[idx] = run;
        run += c;
    }
}

// D: atomic-free fill via private LDS cursors (base slice loaded into LDS,
// LDS atomicAdd hands out exact global slots).
__global__ __launch_bounds__(256) void k_fill2(const int2* __restrict__ pairs,
                                               const int* __restrict__ bucketBase,
                                               const int* __restrict__ bucketCount,
                                               const int* __restrict__ cntarr,
                                               int* __restrict__ col, int npp) {
    __shared__ int cur[NPP_MAX];
    int p = blockIdx.x & (NPART - 1);
    int b = blockIdx.x >> 3;
    int lo = p * npp;
    size_t slice = (size_t)(p * KB + b) * npp;
    for (int i = threadIdx.x; i < npp; i += 256) cur[i] = cntarr[slice + i];
    __syncthreads();
    int segBase = bucketBase[p], sz = bucketCount[p];
    int chunk = (sz + KB - 1) / KB;
    int s0 = segBase + b * chunk;
    int s1 = min(segBase + sz, s0 + chunk);
    for (int i = s0 + threadIdx.x; i < s1; i += 256) {
        int2 e = pairs[i];
        int pos = atomicAdd(&cur[e.x - lo], 1);
        col[pos] = e.y;
    }
}

// ---------------- GEMMs (fp32 VALU) — epilogue: row *= dinv[row], store bf16 -----

__global__ __launch_bounds__(256) void k_gemm128(const float* __restrict__ X,
                                                 const float* __restrict__ W,
                                                 const float* __restrict__ dinv,
                                                 unsigned* __restrict__ Hb) {
    __shared__ float Wl[32 * 128];
    __shared__ float Xs[32 * 32];
    int t = threadIdx.x;
    size_t row0 = (size_t)blockIdx.x * 32;
    int r0 = (t >> 5) * 4;
    int c0 = (t & 31) * 4;
    int lr = t >> 3, lk = (t & 7) * 4;
    float acc[4][4] = {};
    for (int kc = 0; kc < 128; kc += 32) {
        __syncthreads();
        for (int idx = t; idx < 1024; idx += 256)
            ((float4*)Wl)[idx] = ((const float4*)W)[kc * 32 + idx];
        *(float4*)(Xs + lr * 32 + lk) =
            *(const float4*)(X + (row0 + lr) * 128 + kc + lk);
        __syncthreads();
        for (int kk = 0; kk < 32; kk += 4) {
            float a[4][4], wv[4][4];
            for (int r = 0; r < 4; r++) {
                float4 av = *(const float4*)(Xs + (r0 + r) * 32 + kk);
                a[r][0] = av.x; a[r][1] = av.y; a[r][2] = av.z; a[r][3] = av.w;
            }
            for (int j = 0; j < 4; j++) {
                float4 wq = *(const float4*)(Wl + (kk + j) * 128 + c0);
                wv[j][0] = wq.x; wv[j][1] = wq.y; wv[j][2] = wq.z; wv[j][3] = wq.w;
            }
            for (int r = 0; r < 4; r++)
                for (int j = 0; j < 4; j++)
                    for (int c = 0; c < 4; c++)
                        acc[r][c] += a[r][j] * wv[j][c];
        }
    }
    for (int r = 0; r < 4; r++) {
        float di = dinv[row0 + r0 + r];
        uint2 o = {pack_bf16x2(di * acc[r][0], di * acc[r][1]),
                   pack_bf16x2(di * acc[r][2], di * acc[r][3])};
        *(uint2*)(Hb + (row0 + r0 + r) * 64 + (c0 >> 1)) = o;
    }
}

__global__ __launch_bounds__(256) void k_gemm64(const float* __restrict__ X,
                                                const float* __restrict__ W,
                                                const float* __restrict__ dinv,
                                                unsigned* __restrict__ Hb) {
    __shared__ float Wl[32 * 64];
    __shared__ float Xs[32 * 32];
    int t = threadIdx.x;
    size_t row0 = (size_t)blockIdx.x * 32;
    int r0 = (t >> 4) * 2;
    int c0 = (t & 15) * 4;
    int lr = t >> 3, lk = (t & 7) * 4;
    float acc[2][4] = {};
    for (int kc = 0; kc < 128; kc += 32) {
        __syncthreads();
        ((float4*)Wl)[t]       = ((const float4*)W)[kc * 16 + t];
        ((float4*)Wl)[t + 256] = ((const float4*)W)[kc * 16 + t + 256];
        *(float4*)(Xs + lr * 32 + lk) =
            *(const float4*)(X + (row0 + lr) * 128 + kc + lk);
        __syncthreads();
        for (int kk = 0; kk < 32; kk += 4) {
            float a[2][4], wv[4][4];
            for (int r = 0; r < 2; r++) {
                float4 av = *(const float4*)(Xs + (r0 + r) * 32 + kk);
                a[r][0] = av.x; a[r][1] = av.y; a[r][2] = av.z; a[r][3] = av.w;
            }
            for (int j = 0; j < 4; j++) {
                float4 wq = *(const float4*)(Wl + (kk + j) * 64 + c0);
                wv[j][0] = wq.x; wv[j][1] = wq.y; wv[j][2] = wq.z; wv[j][3] = wq.w;
            }
            for (int r = 0; r < 2; r++)
                for (int j = 0; j < 4; j++)
                    for (int c = 0; c < 4; c++)
                        acc[r][c] += a[r][j] * wv[j][c];
        }
    }
    for (int r = 0; r < 2; r++) {
        float di = dinv[row0 + r0 + r];
        uint2 o = {pack_bf16x2(di * acc[r][0], di * acc[r][1]),
                   pack_bf16x2(di * acc[r][2], di * acc[r][3])};
        *(uint2*)(Hb + (row0 + r0 + r) * 32 + (c0 >> 1)) = o;
    }
}

// ---------------- Pull-mode aggregation (bf16 payload, fp32 accumulate) ----------

__global__ __launch_bounds__(256) void k_agg_relu(const unsigned* __restrict__ hs,
                                                  const float* __restrict__ dinv,
                                                  const int* __restrict__ row_ptr,
                                                  const int* __restrict__ col,
                                                  const float* __restrict__ bias,
                                                  float* __restrict__ out, int n) {
    int node = blockIdx.x * 4 + (threadIdx.x >> 6);
    if (node >= n) return;
    int lane = threadIdx.x & 63;
    unsigned su = hs[(size_t)node * 64 + lane];
    float ax = bf16lo(su), ay = bf16hi(su);
    int p0 = row_ptr[node], p1 = row_ptr[node + 1];
    for (int base = p0; base < p1; base += 64) {
        int nb = min(64, p1 - base);
        int myc = col[base + min(lane, nb - 1)];
        int k = 0;
        for (; k + 4 <= nb; k += 4) {
            int j0 = __shfl(myc, k);
            int j1 = __shfl(myc, k + 1);
            int j2 = __shfl(myc, k + 2);
            int j3 = __shfl(myc, k + 3);
            unsigned v0 = hs[(size_t)j0 * 64 + lane];
            unsigned v1 = hs[(size_t)j1 * 64 + lane];
            unsigned v2 = hs[(size_t)j2 * 64 + lane];
            unsigned v3 = hs[(size_t)j3 * 64 + lane];
            ax += (bf16lo(v0) + bf16lo(v1)) + (bf16lo(v2) + bf16lo(v3));
            ay += (bf16hi(v0) + bf16hi(v1)) + (bf16hi(v2) + bf16hi(v3));
        }
        for (; k < nb; ++k) {
            int j = __shfl(myc, k);
            unsigned v = hs[(size_t)j * 64 + lane];
            ax += bf16lo(v);
            ay += bf16hi(v);
        }
    }
    float di = dinv[node];
    ax = fmaf(di, ax, bias[2 * lane]);
    ay = fmaf(di, ay, bias[2 * lane + 1]);
    ax = ax > 0.f ? ax : 0.f;
    ay = ay > 0.f ? ay : 0.f;
    float2 o = {ax, ay};
    ((float2*)out)[(size_t)node * 64 + lane] = o;
}

__global__ __launch_bounds__(256) void k_agg_lsm(const unsigned short* __restrict__ hs,
                                                 const float* __restrict__ dinv,
                                                 const int* __restrict__ row_ptr,
                                                 const int* __restrict__ col,
                                                 const float* __restrict__ bias,
                                                 float* __restrict__ out, int n) {
    int node = blockIdx.x * 4 + (threadIdx.x >> 6);
    if (node >= n) return;
    int lane = threadIdx.x & 63;
    float acc = __uint_as_float(((unsigned)hs[(size_t)node * 64 + lane]) << 16);
    int p0 = row_ptr[node], p1 = row_ptr[node + 1];
    for (int base = p0; base < p1; base += 64) {
        int nb = min(64, p1 - base);
        int myc = col[base + min(lane, nb - 1)];
        int k = 0;
        for (; k + 4 <= nb; k += 4) {
            int j0 = __shfl(myc, k);
            int j1 = __shfl(myc, k + 1);
            int j2 = __shfl(myc, k + 2);
            int j3 = __shfl(myc, k + 3);
            float v0 = __uint_as_float(((unsigned)hs[(size_t)j0 * 64 + lane]) << 16);
            float v1 = __uint_as_float(((unsigned)hs[(size_t)j1 * 64 + lane]) << 16);
            float v2 = __uint_as_float(((unsigned)hs[(size_t)j2 * 64 + lane]) << 16);
            float v3 = __uint_as_float(((unsigned)hs[(size_t)j3 * 64 + lane]) << 16);
            acc += (v0 + v1) + (v2 + v3);
        }
        for (; k < nb; ++k) {
            int j = __shfl(myc, k);
            acc += __uint_as_float(((unsigned)hs[(size_t)j * 64 + lane]) << 16);
        }
    }
    float v = fmaf(dinv[node], acc, bias[lane]);
    float m = v;
    for (int off = 32; off; off >>= 1) m = fmaxf(m, __shfl_xor(m, off));
    float e = __expf(v - m);
    float s = e;
    for (int off = 32; off; off >>= 1) s += __shfl_xor(s, off);
    out[(size_t)node * 64 + lane] = v - m - __logf(s);
}

// ---------------- launcher ----------------

extern "C" void kernel_launch(void* const* d_in, const int* in_sizes, int n_in,
                              void* d_out, int out_size, void* d_ws, size_t ws_size,
                              hipStream_t stream) {
    const float* x  = (const float*)d_in[0];
    const int*   ei = (const int*)d_in[1];
    const float* W1 = (const float*)d_in[2];
    const float* b1 = (const float*)d_in[3];
    const float* W2 = (const float*)d_in[4];
    const float* b2 = (const float*)d_in[5];
    float* out = (float*)d_out;

    const int N = in_sizes[0] / 128;   // 100000
    const int E = in_sizes[1] / 2;     // 1600000
    const int* src = ei;       // edge_index[0]
    const int* dst = ei + E;   // edge_index[1]
    const int npp = (N + NPART - 1) / NPART;  // 12500 (<= NPP_MAX)

    // workspace carve (256B aligned)
    char* w = (char*)d_ws;
    size_t off = 0;
    auto alloc = [&](size_t bytes) -> void* {
        void* p = w + off;
        off += (bytes + 255) & ~(size_t)255;
        return p;
    };
    int*      indeg    = (int*)alloc((size_t)N * 4);
    int*      row_ptr  = (int*)alloc((size_t)(N + 1) * 4);
    int*      colarr   = (int*)alloc((size_t)E * 4);
    int*      partials = (int*)alloc(256 * 4);
    int*      bmeta    = (int*)alloc(16 * 4);  // [0..7]=count, [8..15]=cursor
    int*      bbase    = (int*)alloc(NPART * 4);
    float*    dinv     = (float*)alloc((size_t)N * 4);
    unsigned* h1b      = (unsigned*)alloc((size_t)N * 64 * 4);   // bf16 X@W1 scaled
    float*    a1       = (float*)alloc((size_t)N * 128 * 4);     // relu out (fp32)
    unsigned* h2b      = (unsigned*)alloc((size_t)N * 32 * 4);   // bf16 a1@W2 scaled
    // CSR-build temporaries overlay a1 (dead until gemm128): pairs + partial counts
    int2* pairs  = (int2*)a1;                                    // E*8 = 12.8 MB
    int*  cntarr = (int*)((char*)a1 + (size_t)E * 8);            // 8*32*npp*4 = 12.8 MB
    (void)ws_size; (void)n_in; (void)out_size;

    int* bucketCount  = bmeta;
    int* bucketCursor = bmeta + 8;
    int nscan = (N + 1023) / 1024;
    int nA3 = (E + 4095) / 4096;

    k_zero16<<<1, 64, 0, stream>>>(bmeta);
    k_bcount<<<256, 256, 0, stream>>>(dst, bucketCount, E, npp);
    k_bscan<<<1, 64, 0, stream>>>(bucketCount, bbase, bucketCursor);
    k_bucket<<<nA3, 256, 0, stream>>>(src, dst, bucketCursor, pairs, E, npp);
    k_count_part<<<NPART * KB, 256, 0, stream>>>(pairs, bbase, bucketCount, cntarr, npp);
    k_indeg<<<(N + 255) / 256, 256, 0, stream>>>(cntarr, indeg, N, npp);
    k_scan_local<<<nscan, 256, 0, stream>>>(indeg, row_ptr, partials, N);
    k_scan_partials<<<1, 256, 0, stream>>>(partials, nscan);
    k_finalize<<<(N + 255) / 256, 256, 0, stream>>>(row_ptr, partials, indeg, dinv, N, E);
    k_bases<<<(N + 255) / 256, 256, 0, stream>>>(cntarr, row_ptr, N, npp);
    k_fill2<<<NPART * KB, 256, 0, stream>>>(pairs, bbase, bucketCount, cntarr,
                                            colarr, npp);

    k_gemm128<<<N / 32, 256, 0, stream>>>(x, W1, dinv, h1b);
    k_agg_relu<<<(N + 3) / 4, 256, 0, stream>>>(h1b, dinv, row_ptr, colarr, b1, a1, N);
    k_gemm64<<<N / 32, 256, 0, stream>>>(a1, W2, dinv, h2b);
    k_agg_lsm<<<(N + 3) / 4, 256, 0, stream>>>((const unsigned short*)h2b, dinv,
                                               row_ptr, colarr, b2, out, N);
}